// Round 10
// baseline (671.126 us; speedup 1.0000x reference)
//
#include <hip/hip_runtime.h>
#include <hip/hip_bf16.h>
#include <math.h>

#define S_LEN 2048
#define D_DIM 2048
#define NH 32
#define HD 64
#define CS 256
#define NCH 8

typedef __attribute__((ext_vector_type(8))) short bf16x8;
typedef __attribute__((ext_vector_type(4))) short bf16x4;
typedef __attribute__((ext_vector_type(4))) float f32x4;

__device__ __forceinline__ unsigned short f2bf(float f) {
  unsigned int u = __builtin_bit_cast(unsigned int, f);
  unsigned int r = (u + 0x7fffu + ((u >> 16) & 1u)) >> 16;
  return (unsigned short)r;
}
__device__ __forceinline__ float bf2f(unsigned short b) {
  unsigned int u = ((unsigned int)b) << 16;
  return __builtin_bit_cast(float, u);
}

__device__ __forceinline__ f32x4 mfma16(bf16x4 a, bf16x4 b, f32x4 c) {
#if __has_builtin(__builtin_amdgcn_mfma_f32_16x16x16_bf16)
  return __builtin_amdgcn_mfma_f32_16x16x16_bf16(a, b, c, 0, 0, 0);
#elif __has_builtin(__builtin_amdgcn_mfma_f32_16x16x16bf16_1k)
  return __builtin_amdgcn_mfma_f32_16x16x16bf16_1k(a, b, c, 0, 0, 0);
#else
  asm("v_mfma_f32_16x16x16_bf16 %0, %1, %2, %0" : "+v"(c) : "v"(a), "v"(b));
  return c;
#endif
}

__device__ __forceinline__ void gload16(const void* gp, void* lp) {
  __builtin_amdgcn_global_load_lds(
      (const __attribute__((address_space(1))) unsigned int*)gp,
      (__attribute__((address_space(3))) unsigned int*)lp, 16, 0, 0);
}

// ---------------------------------------------------------------------------
// Fused QKVG GEMM. Grid = 4*512 blocks; out = bid>>9 selects {Q,K,V,G}.
// Each block: 64x128 tile of C[out] = sum_p A_p @ B_p^T, M=N=K=2048.
// Q,K: 3 passes (xh*Wh, xh*Wl, xl*Wh); V,G: 1 pass (xh*Wh).
// ---------------------------------------------------------------------------
struct QKVG {
  const unsigned short* xh;
  const unsigned short* xl;
  const unsigned short* wh[4];
  const unsigned short* wl[4];
  float* C[4];
  int np[4];
};

__global__ __launch_bounds__(256) void gemm_qkvg(QKVG g) {
  __shared__ __align__(16) unsigned short Als[64 * 64];
  __shared__ __align__(16) unsigned short Bls[128 * 64];
  const int tid = threadIdx.x;
  const int wid = tid >> 6, lane = tid & 63;
  const int l15 = lane & 15, l4 = lane >> 4;
  const int wr = wid >> 1, wc = wid & 1;
  const int K = D_DIM, N = D_DIM;
  // XCD swizzle over the whole 2048-block grid
  int bidS = (blockIdx.x & 7) * 256 + (blockIdx.x >> 3);
  const int out = bidS >> 9;
  const int b2 = bidS & 511;
  const int row0 = (b2 >> 4) << 6;   // 32 row-tiles
  const int col0 = (b2 & 15) << 7;   // 16 col-tiles

  f32x4 acc[2][4];
#pragma unroll
  for (int m = 0; m < 2; ++m)
#pragma unroll
    for (int n = 0; n < 4; ++n) acc[m][n] = (f32x4){0.f, 0.f, 0.f, 0.f};

  const int np = g.np[out];
  for (int p = 0; p < np; ++p) {
    const unsigned short* Ap = (p == 2) ? g.xl : g.xh;
    const unsigned short* Bp = (p == 1) ? g.wl[out] : g.wh[out];
    for (int kt = 0; kt < K; kt += 64) {
      __syncthreads();
#pragma unroll
      for (int i = 0; i < 2; ++i) {
        const int Lb = i * 4096 + wid * 1024;
        const int L = Lb + lane * 16;
        const int row = L >> 7;
        const int s = (L >> 4) & 7;
        const int cofs = (s ^ (row & 7)) << 3;
        gload16(Ap + (size_t)(row0 + row) * K + kt + cofs, (char*)Als + Lb);
      }
#pragma unroll
      for (int i = 0; i < 4; ++i) {
        const int Lb = i * 4096 + wid * 1024;
        const int L = Lb + lane * 16;
        const int row = L >> 7;
        const int s = (L >> 4) & 7;
        const int cofs = (s ^ (row & 7)) << 3;
        gload16(Bp + (size_t)(col0 + row) * K + kt + cofs, (char*)Bls + Lb);
      }
      asm volatile("s_waitcnt vmcnt(0)" ::: "memory");
      __syncthreads();
#pragma unroll
      for (int ks = 0; ks < 2; ++ks) {
        bf16x8 af[2], bfr[4];
#pragma unroll
        for (int m = 0; m < 2; ++m) {
          int row = wr * 32 + m * 16 + l15;
          int s = (ks * 4 + l4) ^ (row & 7);
          af[m] = *reinterpret_cast<const bf16x8*>(&Als[row * 64 + s * 8]);
        }
#pragma unroll
        for (int n = 0; n < 4; ++n) {
          int col = wc * 64 + n * 16 + l15;
          int s = (ks * 4 + l4) ^ (col & 7);
          bfr[n] = *reinterpret_cast<const bf16x8*>(&Bls[col * 64 + s * 8]);
        }
#pragma unroll
        for (int m = 0; m < 2; ++m)
#pragma unroll
          for (int n = 0; n < 4; ++n)
            acc[m][n] = __builtin_amdgcn_mfma_f32_16x16x32_bf16(af[m], bfr[n], acc[m][n], 0, 0, 0);
      }
    }
  }

  float* C = g.C[out];
#pragma unroll
  for (int m = 0; m < 2; ++m)
#pragma unroll
    for (int n = 0; n < 4; ++n)
#pragma unroll
      for (int r = 0; r < 4; ++r)
        C[(size_t)(row0 + wr * 32 + m * 16 + l4 * 4 + r) * N + col0 + wc * 64 + n * 16 + l15] =
            acc[m][n][r];
}

// ---------------------------------------------------------------------------
// bf16 MFMA GEMM (single/multi-pass), kept for the out-projection.
// ---------------------------------------------------------------------------
struct G3 {
  const unsigned short* A[3];
  const unsigned short* B[3];
  int np;
};

__global__ __launch_bounds__(256) void gemm_bt(G3 g, float* __restrict__ C,
                                               int M, int N, int K) {
  __shared__ __align__(16) unsigned short Als[64 * 64];
  __shared__ __align__(16) unsigned short Bls[128 * 64];
  const int tid = threadIdx.x;
  const int wid = tid >> 6, lane = tid & 63;
  const int l15 = lane & 15, l4 = lane >> 4;
  const int wr = wid >> 1, wc = wid & 1;
  const int nbx = N >> 7;
  int bid = blockIdx.x;
  const int nwg = gridDim.x;
  if ((nwg & 7) == 0) {
    int q = nwg >> 3;
    bid = (bid & 7) * q + (bid >> 3);
  }
  const int row0 = (bid / nbx) << 6;
  const int col0 = (bid % nbx) << 7;

  f32x4 acc[2][4];
#pragma unroll
  for (int m = 0; m < 2; ++m)
#pragma unroll
    for (int n = 0; n < 4; ++n) acc[m][n] = (f32x4){0.f, 0.f, 0.f, 0.f};

  for (int p = 0; p < g.np; ++p) {
    const unsigned short* Ap = g.A[p];
    const unsigned short* Bp = g.B[p];
    for (int kt = 0; kt < K; kt += 64) {
      __syncthreads();
#pragma unroll
      for (int i = 0; i < 2; ++i) {
        const int Lb = i * 4096 + wid * 1024;
        const int L = Lb + lane * 16;
        const int row = L >> 7;
        const int s = (L >> 4) & 7;
        const int cofs = (s ^ (row & 7)) << 3;
        gload16(Ap + (size_t)(row0 + row) * K + kt + cofs, (char*)Als + Lb);
      }
#pragma unroll
      for (int i = 0; i < 4; ++i) {
        const int Lb = i * 4096 + wid * 1024;
        const int L = Lb + lane * 16;
        const int row = L >> 7;
        const int s = (L >> 4) & 7;
        const int cofs = (s ^ (row & 7)) << 3;
        gload16(Bp + (size_t)(col0 + row) * K + kt + cofs, (char*)Bls + Lb);
      }
      asm volatile("s_waitcnt vmcnt(0)" ::: "memory");
      __syncthreads();
#pragma unroll
      for (int ks = 0; ks < 2; ++ks) {
        bf16x8 af[2], bfr[4];
#pragma unroll
        for (int m = 0; m < 2; ++m) {
          int row = wr * 32 + m * 16 + l15;
          int s = (ks * 4 + l4) ^ (row & 7);
          af[m] = *reinterpret_cast<const bf16x8*>(&Als[row * 64 + s * 8]);
        }
#pragma unroll
        for (int n = 0; n < 4; ++n) {
          int col = wc * 64 + n * 16 + l15;
          int s = (ks * 4 + l4) ^ (col & 7);
          bfr[n] = *reinterpret_cast<const bf16x8*>(&Bls[col * 64 + s * 8]);
        }
#pragma unroll
        for (int m = 0; m < 2; ++m)
#pragma unroll
          for (int n = 0; n < 4; ++n)
            acc[m][n] = __builtin_amdgcn_mfma_f32_16x16x32_bf16(af[m], bfr[n], acc[m][n], 0, 0, 0);
      }
    }
  }

#pragma unroll
  for (int m = 0; m < 2; ++m)
#pragma unroll
    for (int n = 0; n < 4; ++n)
#pragma unroll
      for (int r = 0; r < 4; ++r)
        C[(size_t)(row0 + wr * 32 + m * 16 + l4 * 4 + r) * N + col0 + wc * 64 + n * 16 + l15] =
            acc[m][n][r];
}

// ---------------------------------------------------------------------------
// fp32 SGEMM (kept only for W' = Wg1 @ Wg2, K=64).
// ---------------------------------------------------------------------------
__global__ __launch_bounds__(256) void sgemm_f32(const float* __restrict__ A,
                                                 const float* __restrict__ B,
                                                 float* __restrict__ C,
                                                 int M, int N, int K) {
  __shared__ float As[8][128];
  __shared__ float Bs[8][128];
  const int tid = threadIdx.x;
  const int row0 = blockIdx.y * 128;
  const int col0 = blockIdx.x * 128;
  const int tm = (tid / 16) * 8;
  const int tn = (tid % 16) * 8;
  const int arow = tid >> 1;
  const int acol = (tid & 1) * 4;
  const int brow = tid >> 5;
  const int bcol = (tid & 31) * 4;

  float acc[8][8];
#pragma unroll
  for (int i = 0; i < 8; ++i)
#pragma unroll
    for (int j = 0; j < 8; ++j) acc[i][j] = 0.f;

  for (int k0 = 0; k0 < K; k0 += 8) {
    float4 av = make_float4(0.f, 0.f, 0.f, 0.f);
    if (row0 + arow < M) {
      int kb = k0 + acol;
      av = *reinterpret_cast<const float4*>(&A[(size_t)(row0 + arow) * K + kb]);
    }
    As[acol + 0][arow] = av.x;
    As[acol + 1][arow] = av.y;
    As[acol + 2][arow] = av.z;
    As[acol + 3][arow] = av.w;
    float4 bv = make_float4(0.f, 0.f, 0.f, 0.f);
    if (k0 + brow < K) {
      bv = *reinterpret_cast<const float4*>(&B[(size_t)(k0 + brow) * N + col0 + bcol]);
    }
    *reinterpret_cast<float4*>(&Bs[brow][bcol]) = bv;
    __syncthreads();
#pragma unroll
    for (int kk = 0; kk < 8; ++kk) {
      float a[8], b[8];
      *reinterpret_cast<float4*>(&a[0]) = *reinterpret_cast<const float4*>(&As[kk][tm]);
      *reinterpret_cast<float4*>(&a[4]) = *reinterpret_cast<const float4*>(&As[kk][tm + 4]);
      *reinterpret_cast<float4*>(&b[0]) = *reinterpret_cast<const float4*>(&Bs[kk][tn]);
      *reinterpret_cast<float4*>(&b[4]) = *reinterpret_cast<const float4*>(&Bs[kk][tn + 4]);
#pragma unroll
      for (int i = 0; i < 8; ++i)
#pragma unroll
        for (int j = 0; j < 8; ++j) acc[i][j] = fmaf(a[i], b[j], acc[i][j]);
    }
    __syncthreads();
  }
#pragma unroll
  for (int i = 0; i < 8; ++i) {
    int r = row0 + tm + i;
    if (r < M) {
#pragma unroll
      for (int j = 0; j < 8; ++j) {
        int c = col0 + tn + j;
        if (c < N) C[(size_t)r * N + c] = acc[i][j];
      }
    }
  }
}

// ---------------------------------------------------------------------------
// x fp32 -> xh, xl bf16 (hi/lo split), same layout.
// ---------------------------------------------------------------------------
__global__ __launch_bounds__(256) void repack_x_hl(const float* __restrict__ x,
                                                   unsigned short* __restrict__ xh,
                                                   unsigned short* __restrict__ xl) {
  int i = (blockIdx.x * 256 + threadIdx.x) * 4;
  float4 v = *reinterpret_cast<const float4*>(&x[i]);
  float f[4] = {v.x, v.y, v.z, v.w};
  unsigned short h[4], l[4];
#pragma unroll
  for (int j = 0; j < 4; ++j) {
    h[j] = f2bf(f[j]);
    l[j] = f2bf(f[j] - bf2f(h[j]));
  }
  *reinterpret_cast<ushort4*>(&xh[i]) = make_ushort4(h[0], h[1], h[2], h[3]);
  *reinterpret_cast<ushort4*>(&xl[i]) = make_ushort4(l[0], l[1], l[2], l[3]);
}

// ---------------------------------------------------------------------------
// W (rows x cols, fp32) -> W^T bf16 hi (and optional lo), (cols x rows).
// ---------------------------------------------------------------------------
__global__ __launch_bounds__(256) void repack_T(const float* __restrict__ W,
                                                unsigned short* __restrict__ hiT,
                                                unsigned short* __restrict__ loT,
                                                int rows, int cols, int has_lo) {
  __shared__ float t[64][65];
  const int k0 = blockIdx.y * 64, n0 = blockIdx.x * 64;
  const int tid = threadIdx.x;
  const int c = tid & 63, rr = tid >> 6;
#pragma unroll
  for (int r = 0; r < 16; ++r) {
    int kr = r * 4 + rr;
    t[kr][c] = W[(size_t)(k0 + kr) * cols + n0 + c];
  }
  __syncthreads();
#pragma unroll
  for (int r = 0; r < 16; ++r) {
    int n = r * 4 + rr;
    float f = t[c][n];
    unsigned short hb = f2bf(f);
    hiT[(size_t)(n0 + n) * rows + k0 + c] = hb;
    if (has_lo) loT[(size_t)(n0 + n) * rows + k0 + c] = f2bf(f - bf2f(hb));
  }
}

// ---------------------------------------------------------------------------
// RoPE applied in-place to q and k.
// ---------------------------------------------------------------------------
__global__ __launch_bounds__(256) void rope_qk(float* __restrict__ q, float* __restrict__ kk) {
  int idx = blockIdx.x * 256 + threadIdx.x;
  if (idx >= S_LEN * NH * (HD / 2)) return;
  int d = idx & 31;
  int sh = idx >> 5;
  int s = sh >> 5;
  float inv = 1.0f / powf(10000.0f, (float)d * (1.0f / 32.0f));
  float fr = (float)s * inv;
  float c = cosf(fr), sn = sinf(fr);
  size_t base = (size_t)sh * HD + d;
  float q1 = q[base], q2 = q[base + 32];
  q[base] = q1 * c - q2 * sn;
  q[base + 32] = q2 * c + q1 * sn;
  float k1 = kk[base], k2 = kk[base + 32];
  kk[base] = k1 * c - k2 * sn;
  kk[base + 32] = k2 * c + k1 * sn;
}

// ---------------------------------------------------------------------------
// Chunk means of k.
// ---------------------------------------------------------------------------
__global__ __launch_bounds__(256) void chunk_mean(const float* __restrict__ k,
                                                  float* __restrict__ kg) {
  int idx = blockIdx.x * 256 + threadIdx.x;
  if (idx >= NCH * NH * HD) return;
  int c = idx / (NH * HD);
  int hd = idx % (NH * HD);
  float sum = 0.f;
  for (int t = 0; t < CS; ++t) sum += k[(size_t)(c * CS + t) * (NH * HD) + hd];
  kg[idx] = sum * (1.0f / CS);
}

// ---------------------------------------------------------------------------
// Gate + top-3-past chunk selection (fp32 — selection must stay exact).
// ---------------------------------------------------------------------------
__global__ __launch_bounds__(256) void gate_topk(const float* __restrict__ q,
                                                 const float* __restrict__ kg,
                                                 int* __restrict__ amask) {
  int wid = threadIdx.x >> 6;
  int lane = threadIdx.x & 63;
  int s = blockIdx.x * 4 + wid;
  int h = blockIdx.y;
  int myc = s >> 8;
  float qd = q[((size_t)s * NH + h) * HD + lane];
  float g[NCH];
#pragma unroll
  for (int c = 0; c < NCH; ++c) {
    float p = qd * kg[((size_t)c * NH + h) * HD + lane];
#pragma unroll
    for (int off = 32; off; off >>= 1) p += __shfl_xor(p, off);
    g[c] = p;
  }
  int chosen = 0;
#pragma unroll
  for (int pick = 0; pick < 3; ++pick) {
    float best = -INFINITY;
    int bi = -1;
#pragma unroll
    for (int c = 0; c < NCH; ++c) {
      if (c < myc && !((chosen >> c) & 1) && g[c] > best) {
        best = g[c];
        bi = c;
      }
    }
    if (bi >= 0) chosen |= (1 << bi);
  }
  int mask = chosen | (1 << myc);
  if (lane == 0) amask[h * S_LEN + s] = mask;
}

// ---------------------------------------------------------------------------
// Repack k fp32 [s][h][d] -> kh bf16 [h][s][d]
// ---------------------------------------------------------------------------
__global__ __launch_bounds__(256) void repack_k(const float* __restrict__ k,
                                                unsigned short* __restrict__ kh) {
  int t = blockIdx.x * 256 + threadIdx.x;
  int d4 = (t & 15) * 4;
  int s = (t >> 4) & (S_LEN - 1);
  int h = t >> 15;
  float4 v = *reinterpret_cast<const float4*>(&k[(((size_t)s * NH + h) * HD + d4)]);
  size_t oi = ((size_t)h * S_LEN + s) * HD + d4;
  *reinterpret_cast<ushort4*>(&kh[oi]) =
      make_ushort4(f2bf(v.x), f2bf(v.y), f2bf(v.z), f2bf(v.w));
}

// ---------------------------------------------------------------------------
// Repack v fp32 [s][h][d] -> vT bf16 [h][d][s]  (LDS transpose)
// ---------------------------------------------------------------------------
__global__ __launch_bounds__(256) void repack_vT(const float* __restrict__ v,
                                                 unsigned short* __restrict__ vT) {
  __shared__ float tile[64][65];
  const int h = blockIdx.y;
  const int sb = blockIdx.x * 64;
  const int tid = threadIdx.x;
#pragma unroll
  for (int r = 0; r < 16; ++r) {
    int row = r * 4 + (tid >> 6);
    int d = tid & 63;
    tile[row][d] = v[((size_t)(sb + row) * NH + h) * HD + d];
  }
  __syncthreads();
#pragma unroll
  for (int r = 0; r < 16; ++r) {
    int d = r * 4 + (tid >> 6);
    int si = tid & 63;
    vT[((size_t)h * HD + d) * S_LEN + sb + si] = f2bf(tile[si][d]);
  }
}

// ---------------------------------------------------------------------------
// MFMA flash attention — independent waves (no split-K, no LDS merge).
// Each wave owns 16 q-rows; 4 waves per block share a head for L2 locality.
// Grid 1024 blocks; XCD (bid&7) keeps heads {x, x+8, x+16, x+24} local.
// Heavy s-blocks scheduled first. Numerics identical to R9.
// ---------------------------------------------------------------------------
__global__ __launch_bounds__(256) void attn_mfma(const float* __restrict__ q,
                                                 const unsigned short* __restrict__ kh,
                                                 const unsigned short* __restrict__ vT,
                                                 const int* __restrict__ amask,
                                                 float* __restrict__ o) {
  const int B = blockIdx.x;
  const int xcd = B & 7;
  const int t = B >> 3;            // 0..127
  const int h = xcd + ((t >> 5) << 3);
  const int g2 = 31 - (t & 31);    // reversed: heavy (high-s) blocks first
  const int tid = threadIdx.x;
  const int wid = tid >> 6;
  const int lane = tid & 63;
  const int l15 = lane & 15, g = lane >> 4;
  const int s0 = g2 * 64 + wid * 16;
  const int myS = s0 + l15;
  const int myc = s0 >> 8;
  const int ktm = (s0 & (CS - 1)) >> 6;

  // Q B-frag, scale 1/8 folded (exact for pow2)
  const float* qrow = q + ((size_t)myS * NH + h) * HD;
  bf16x8 qf[2];
#pragma unroll
  for (int hf = 0; hf < 2; ++hf)
#pragma unroll
    for (int jj = 0; jj < 8; ++jj)
      qf[hf][jj] = (short)f2bf(qrow[hf * 32 + g * 8 + jj] * 0.125f);

  int mymask = amask[h * S_LEN + myS];
  int wmask = mymask;
  wmask |= __shfl_xor(wmask, 1);
  wmask |= __shfl_xor(wmask, 2);
  wmask |= __shfl_xor(wmask, 4);
  wmask |= __shfl_xor(wmask, 8);
  const int pmask = wmask & ~(1 << myc);
  const int ntot = (ktm + 1) + 4 * __popc(pmask);

  // j -> (t0 | lane_on<<16). Self-chunk tiles first, then past chunks.
  auto DEC = [&](int j) -> int {
    if (j <= ktm) return ((s0 & ~255) + (j << 6)) | (1 << 16);
    int jj = j - ktm - 1;
    int mm = pmask;
    int drop = jj >> 2;
    for (int b = 0; b < drop; ++b) mm &= mm - 1;
    int c = __ffs(mm) - 1;
    return ((c << 8) + ((jj & 3) << 6)) | (((mymask >> c) & 1) << 16);
  };

  const unsigned short* khh = kh + (size_t)h * S_LEN * HD;
  const unsigned short* vth = vT + (size_t)h * HD * S_LEN;

  bf16x8 kr[4][2];
  auto LOADK = [&](int t0) {
#pragma unroll
    for (int st = 0; st < 4; ++st) {
      const unsigned short* kp = khh + (size_t)(t0 + st * 16 + l15) * HD + g * 8;
      kr[st][0] = *reinterpret_cast<const bf16x8*>(kp);
      kr[st][1] = *reinterpret_cast<const bf16x8*>(kp + 32);
    }
  };

  float m = -1e30f, lsum = 0.f;
  f32x4 accv[4];
#pragma unroll
  for (int i = 0; i < 4; ++i) accv[i] = (f32x4){0.f, 0.f, 0.f, 0.f};

  LOADK(DEC(0) & 0xFFFF);

  for (int j = 0; j < ntot; ++j) {
    const int ent = DEC(j);
    const int t0 = ent & 0xFFFF;
    const bool lane_on = (ent >> 16) != 0;
    const bool diag = (j == ktm);

    // V B-frags for this tile (issued early; consumed after softmax)
    bf16x4 vb[4][4];
#pragma unroll
    for (int st = 0; st < 4; ++st)
#pragma unroll
      for (int cb = 0; cb < 4; ++cb)
        vb[st][cb] = *reinterpret_cast<const bf16x4*>(
            vth + (size_t)(cb * 16 + l15) * S_LEN + t0 + st * 16 + 4 * g);

    // QK^T (scale pre-folded into qf)
    float p[16];
    __builtin_amdgcn_s_setprio(1);
#pragma unroll
    for (int st = 0; st < 4; ++st) {
      f32x4 d = (f32x4){0.f, 0.f, 0.f, 0.f};
      d = __builtin_amdgcn_mfma_f32_16x16x32_bf16(kr[st][0], qf[0], d, 0, 0, 0);
      d = __builtin_amdgcn_mfma_f32_16x16x32_bf16(kr[st][1], qf[1], d, 0, 0, 0);
#pragma unroll
      for (int r = 0; r < 4; ++r) {
        bool ok = lane_on && (!diag || (t0 + st * 16 + 4 * g + r <= myS));
        p[st * 4 + r] = ok ? d[r] : -1e30f;
      }
    }
    __builtin_amdgcn_s_setprio(0);

    // Prefetch next tile's K into the same regs (WAR-ordered); latency
    // hides under softmax+PV below.
    if (j + 1 < ntot) LOADK(DEC(j + 1) & 0xFFFF);

    // Row max (4-lane groups share a row via xor 16/32)
    float mt = -1e30f;
#pragma unroll
    for (int ii = 0; ii < 16; ++ii) mt = fmaxf(mt, p[ii]);
    mt = fmaxf(mt, __shfl_xor(mt, 16));
    mt = fmaxf(mt, __shfl_xor(mt, 32));

    const float mnew = fmaxf(m, mt);
    const float corr = __expf(m - mnew);
    float ps = 0.f;
#pragma unroll
    for (int ii = 0; ii < 16; ++ii) {
      float pv = (p[ii] > -1e29f) ? __expf(p[ii] - mnew) : 0.f;
      p[ii] = pv;
      ps += pv;
    }
    ps += __shfl_xor(ps, 16);
    ps += __shfl_xor(ps, 32);
    lsum = lsum * corr + ps;
    m = mnew;

    // Rescale accumulator (acc rows are q-rows 4g+r; corr lives at lane 4g+r)
#pragma unroll
    for (int r = 0; r < 4; ++r) {
      float cr = __shfl(corr, 4 * g + r);
#pragma unroll
      for (int cb = 0; cb < 4; ++cb) accv[cb][r] *= cr;
    }

    // PV: P fragment (A of 16x16x16) is exactly the S^T output fragment
    __builtin_amdgcn_s_setprio(1);
#pragma unroll
    for (int st = 0; st < 4; ++st) {
      bf16x4 pa;
#pragma unroll
      for (int jj = 0; jj < 4; ++jj) pa[jj] = (short)f2bf(p[st * 4 + jj]);
#pragma unroll
      for (int cb = 0; cb < 4; ++cb)
        accv[cb] = mfma16(pa, vb[st][cb], accv[cb]);
    }
    __builtin_amdgcn_s_setprio(0);
  }

  // ---- write out: each wave owns its 16 rows fully ----
  const float inv = 1.0f / lsum;  // per lane, row l15
#pragma unroll
  for (int r = 0; r < 4; ++r) {
    float iv = __shfl(inv, 4 * g + r);
    float* op = o + ((size_t)(s0 + 4 * g + r) * NH + h) * HD + l15;
#pragma unroll
    for (int cb = 0; cb < 4; ++cb) op[cb * 16] = accv[cb][r] * iv;
  }
}

// ---------------------------------------------------------------------------
// RMS-norm + sigmoid gate; emits bf16 for the out-proj A-operand.
// ---------------------------------------------------------------------------
__global__ __launch_bounds__(256) void postproc(const float* __restrict__ o,
                                                const float* __restrict__ g,
                                                const float* __restrict__ w,
                                                unsigned short* __restrict__ o2h) {
  int idx = blockIdx.x * 256 + threadIdx.x;
  int lane = threadIdx.x & 63;
  float val = o[idx];
  float ss = val * val;
#pragma unroll
  for (int off = 32; off; off >>= 1) ss += __shfl_xor(ss, off);
  float r = rsqrtf(ss * (1.0f / HD) + 1e-6f);
  float gv = g[idx];
  float sig = 1.0f / (1.0f + expf(-gv));
  o2h[idx] = f2bf(val * r * w[lane] * sig);
}

// ---------------------------------------------------------------------------
extern "C" void kernel_launch(void* const* d_in, const int* in_sizes, int n_in,
                              void* d_out, int out_size, void* d_ws, size_t ws_size,
                              hipStream_t stream) {
  const float* x   = (const float*)d_in[0];
  const float* Wq  = (const float*)d_in[1];
  const float* Wk  = (const float*)d_in[2];
  const float* Wv  = (const float*)d_in[3];
  const float* Wo  = (const float*)d_in[4];
  const float* Wg1 = (const float*)d_in[5];
  const float* Wg2 = (const float*)d_in[6];
  const float* onw = (const float*)d_in[7];
  float* out = (float*)d_out;

  const size_t BIG = (size_t)S_LEN * D_DIM;  // 4M elements
  float* q    = (float*)d_ws;
  float* k    = q + BIG;
  float* v    = k + BIG;
  float* o    = v + BIG;
  float* gbuf = o + BIG;
  float* kg   = gbuf + BIG;                    // NCH*NH*HD
  int* amask  = (int*)(kg + NCH * NH * HD);    // NH*S
  unsigned short* xh  = (unsigned short*)(amask + NH * S_LEN);
  unsigned short* xl  = xh + BIG;
  unsigned short* whq = xl + BIG;
  unsigned short* wlq = whq + BIG;
  unsigned short* whk = wlq + BIG;
  unsigned short* wlk = whk + BIG;
  unsigned short* whv = wlk + BIG;
  unsigned short* whg = whv + BIG;
  unsigned short* kh  = whg + BIG;
  unsigned short* vT  = kh + BIG;
  unsigned short* o2h = vT + BIG;

  const dim3 gT(32, 32);
  // Split x into hi/lo bf16
  repack_x_hl<<<(int)(BIG / 4 / 256), 256, 0, stream>>>(x, xh, xl);
  // Weight repacks
  repack_T<<<gT, 256, 0, stream>>>(Wq, whq, wlq, D_DIM, D_DIM, 1);
  repack_T<<<gT, 256, 0, stream>>>(Wk, whk, wlk, D_DIM, D_DIM, 1);
  repack_T<<<gT, 256, 0, stream>>>(Wv, whv, nullptr, D_DIM, D_DIM, 0);
  // W' = Wg1 @ Wg2 (fp32, K=64) into o; repack to whg
  sgemm_f32<<<dim3(16, 16), 256, 0, stream>>>(Wg1, Wg2, o, D_DIM, D_DIM, HD);
  repack_T<<<gT, 256, 0, stream>>>(o, whg, nullptr, D_DIM, D_DIM, 0);

  // Fused Q(3) K(3) V(1) G(1) projections — one launch, 2048 blocks
  {
    QKVG gg;
    gg.xh = xh; gg.xl = xl;
    gg.wh[0] = whq; gg.wh[1] = whk; gg.wh[2] = whv; gg.wh[3] = whg;
    gg.wl[0] = wlq; gg.wl[1] = wlk; gg.wl[2] = nullptr; gg.wl[3] = nullptr;
    gg.C[0] = q; gg.C[1] = k; gg.C[2] = v; gg.C[3] = gbuf;
    gg.np[0] = 3; gg.np[1] = 3; gg.np[2] = 1; gg.np[3] = 1;
    gemm_qkvg<<<2048, 256, 0, stream>>>(gg);
  }

  // RoPE
  rope_qk<<<S_LEN * NH * (HD / 2) / 256, 256, 0, stream>>>(q, k);
  // Chunk means + gating (fp32)
  chunk_mean<<<(NCH * NH * HD + 255) / 256, 256, 0, stream>>>(k, kg);
  gate_topk<<<dim3(S_LEN / 4, NH), 256, 0, stream>>>(q, kg, amask);
  // Repack for MFMA attention
  repack_k<<<(int)(BIG / 4 / 256), 256, 0, stream>>>(k, kh);
  repack_vT<<<dim3(S_LEN / 64, NH), 256, 0, stream>>>(v, vT);
  // Attention (overwrites o): independent waves, head-locality XCD swizzle
  attn_mfma<<<(S_LEN / 16) * NH / 4, 256, 0, stream>>>(q, kh, vT, amask, o);
  // RMS-norm + sigmoid gate -> bf16
  postproc<<<(int)(BIG / 256), 256, 0, stream>>>(o, gbuf, onw, o2h);
  // out = o2 @ Wo (1-pass bf16); reuse whq for Wo^T
  repack_T<<<gT, 256, 0, stream>>>(Wo, whq, nullptr, D_DIM, D_DIM, 0);
  {
    G3 g3{{o2h, o2h, o2h}, {whq, whq, whq}, 1};
    gemm_bt<<<(S_LEN / 64) * (D_DIM / 128), 256, 0, stream>>>(g3, out, S_LEN, D_DIM, D_DIM);
  }
}

// Round 11
// 478.953 us; speedup vs baseline: 1.4012x; 1.4012x over previous
//
#include <hip/hip_runtime.h>
#include <hip/hip_bf16.h>
#include <math.h>

#define S_LEN 2048
#define D_DIM 2048
#define NH 32
#define HD 64
#define CS 256
#define NCH 8

typedef __attribute__((ext_vector_type(8))) short bf16x8;
typedef __attribute__((ext_vector_type(4))) short bf16x4;
typedef __attribute__((ext_vector_type(4))) float f32x4;

__device__ __forceinline__ unsigned short f2bf(float f) {
  unsigned int u = __builtin_bit_cast(unsigned int, f);
  unsigned int r = (u + 0x7fffu + ((u >> 16) & 1u)) >> 16;
  return (unsigned short)r;
}
__device__ __forceinline__ float bf2f(unsigned short b) {
  unsigned int u = ((unsigned int)b) << 16;
  return __builtin_bit_cast(float, u);
}

__device__ __forceinline__ f32x4 mfma16(bf16x4 a, bf16x4 b, f32x4 c) {
#if __has_builtin(__builtin_amdgcn_mfma_f32_16x16x16_bf16)
  return __builtin_amdgcn_mfma_f32_16x16x16_bf16(a, b, c, 0, 0, 0);
#elif __has_builtin(__builtin_amdgcn_mfma_f32_16x16x16bf16_1k)
  return __builtin_amdgcn_mfma_f32_16x16x16bf16_1k(a, b, c, 0, 0, 0);
#else
  asm("v_mfma_f32_16x16x16_bf16 %0, %1, %2, %0" : "+v"(c) : "v"(a), "v"(b));
  return c;
#endif
}

__device__ __forceinline__ void gload16(const void* gp, void* lp) {
  __builtin_amdgcn_global_load_lds(
      (const __attribute__((address_space(1))) unsigned int*)gp,
      (__attribute__((address_space(3))) unsigned int*)lp, 16, 0, 0);
}

// ---------------------------------------------------------------------------
// Fused QKVG GEMM. Grid = 4*512 blocks; out selects {Q,K,V,G}.
// Col-group rasterization: within an XCD, blocks walk 4-col-tile groups with
// rows inner, so the resident B working set is 2MB (fits 4MB L2) and weight
// panels are fetched ~once per group instead of once per generation.
// ---------------------------------------------------------------------------
struct QKVG {
  const unsigned short* xh;
  const unsigned short* xl;
  const unsigned short* wh[4];
  const unsigned short* wl[4];
  float* C[4];
  int np[4];
};

__global__ __launch_bounds__(256) void gemm_qkvg(QKVG g) {
  __shared__ __align__(16) unsigned short Als[64 * 64];
  __shared__ __align__(16) unsigned short Bls[128 * 64];
  const int tid = threadIdx.x;
  const int wid = tid >> 6, lane = tid & 63;
  const int l15 = lane & 15, l4 = lane >> 4;
  const int wr = wid >> 1, wc = wid & 1;
  const int K = D_DIM, N = D_DIM;
  // XCD swizzle over the 2048-block grid
  int bidS = (blockIdx.x & 7) * 256 + (blockIdx.x >> 3);
  const int out = bidS >> 9;
  const int b2 = bidS & 511;
  const int grp = b2 >> 7;          // 4 col-groups of 4 col-tiles
  const int idx = b2 & 127;
  const int row0 = (idx >> 2) << 6;               // 32 row-tiles, inner
  const int col0 = (grp * 4 + (idx & 3)) << 7;    // 16 col-tiles

  f32x4 acc[2][4];
#pragma unroll
  for (int m = 0; m < 2; ++m)
#pragma unroll
    for (int n = 0; n < 4; ++n) acc[m][n] = (f32x4){0.f, 0.f, 0.f, 0.f};

  const int np = g.np[out];
  for (int p = 0; p < np; ++p) {
    const unsigned short* Ap = (p == 2) ? g.xl : g.xh;
    const unsigned short* Bp = (p == 1) ? g.wl[out] : g.wh[out];
    for (int kt = 0; kt < K; kt += 64) {
      __syncthreads();
#pragma unroll
      for (int i = 0; i < 2; ++i) {
        const int Lb = i * 4096 + wid * 1024;
        const int L = Lb + lane * 16;
        const int row = L >> 7;
        const int s = (L >> 4) & 7;
        const int cofs = (s ^ (row & 7)) << 3;
        gload16(Ap + (size_t)(row0 + row) * K + kt + cofs, (char*)Als + Lb);
      }
#pragma unroll
      for (int i = 0; i < 4; ++i) {
        const int Lb = i * 4096 + wid * 1024;
        const int L = Lb + lane * 16;
        const int row = L >> 7;
        const int s = (L >> 4) & 7;
        const int cofs = (s ^ (row & 7)) << 3;
        gload16(Bp + (size_t)(col0 + row) * K + kt + cofs, (char*)Bls + Lb);
      }
      asm volatile("s_waitcnt vmcnt(0)" ::: "memory");
      __syncthreads();
#pragma unroll
      for (int ks = 0; ks < 2; ++ks) {
        bf16x8 af[2], bfr[4];
#pragma unroll
        for (int m = 0; m < 2; ++m) {
          int row = wr * 32 + m * 16 + l15;
          int s = (ks * 4 + l4) ^ (row & 7);
          af[m] = *reinterpret_cast<const bf16x8*>(&Als[row * 64 + s * 8]);
        }
#pragma unroll
        for (int n = 0; n < 4; ++n) {
          int col = wc * 64 + n * 16 + l15;
          int s = (ks * 4 + l4) ^ (col & 7);
          bfr[n] = *reinterpret_cast<const bf16x8*>(&Bls[col * 64 + s * 8]);
        }
#pragma unroll
        for (int m = 0; m < 2; ++m)
#pragma unroll
          for (int n = 0; n < 4; ++n)
            acc[m][n] = __builtin_amdgcn_mfma_f32_16x16x32_bf16(af[m], bfr[n], acc[m][n], 0, 0, 0);
      }
    }
  }

  float* C = g.C[out];
#pragma unroll
  for (int m = 0; m < 2; ++m)
#pragma unroll
    for (int n = 0; n < 4; ++n)
#pragma unroll
      for (int r = 0; r < 4; ++r)
        C[(size_t)(row0 + wr * 32 + m * 16 + l4 * 4 + r) * N + col0 + wc * 64 + n * 16 + l15] =
            acc[m][n][r];
}

// ---------------------------------------------------------------------------
// bf16 MFMA GEMM (single/multi-pass), kept for the out-projection.
// ---------------------------------------------------------------------------
struct G3 {
  const unsigned short* A[3];
  const unsigned short* B[3];
  int np;
};

__global__ __launch_bounds__(256) void gemm_bt(G3 g, float* __restrict__ C,
                                               int M, int N, int K) {
  __shared__ __align__(16) unsigned short Als[64 * 64];
  __shared__ __align__(16) unsigned short Bls[128 * 64];
  const int tid = threadIdx.x;
  const int wid = tid >> 6, lane = tid & 63;
  const int l15 = lane & 15, l4 = lane >> 4;
  const int wr = wid >> 1, wc = wid & 1;
  const int nbx = N >> 7;
  int bid = blockIdx.x;
  const int nwg = gridDim.x;
  if ((nwg & 7) == 0) {
    int q = nwg >> 3;
    bid = (bid & 7) * q + (bid >> 3);
  }
  const int row0 = (bid / nbx) << 6;
  const int col0 = (bid % nbx) << 7;

  f32x4 acc[2][4];
#pragma unroll
  for (int m = 0; m < 2; ++m)
#pragma unroll
    for (int n = 0; n < 4; ++n) acc[m][n] = (f32x4){0.f, 0.f, 0.f, 0.f};

  for (int p = 0; p < g.np; ++p) {
    const unsigned short* Ap = g.A[p];
    const unsigned short* Bp = g.B[p];
    for (int kt = 0; kt < K; kt += 64) {
      __syncthreads();
#pragma unroll
      for (int i = 0; i < 2; ++i) {
        const int Lb = i * 4096 + wid * 1024;
        const int L = Lb + lane * 16;
        const int row = L >> 7;
        const int s = (L >> 4) & 7;
        const int cofs = (s ^ (row & 7)) << 3;
        gload16(Ap + (size_t)(row0 + row) * K + kt + cofs, (char*)Als + Lb);
      }
#pragma unroll
      for (int i = 0; i < 4; ++i) {
        const int Lb = i * 4096 + wid * 1024;
        const int L = Lb + lane * 16;
        const int row = L >> 7;
        const int s = (L >> 4) & 7;
        const int cofs = (s ^ (row & 7)) << 3;
        gload16(Bp + (size_t)(col0 + row) * K + kt + cofs, (char*)Bls + Lb);
      }
      asm volatile("s_waitcnt vmcnt(0)" ::: "memory");
      __syncthreads();
#pragma unroll
      for (int ks = 0; ks < 2; ++ks) {
        bf16x8 af[2], bfr[4];
#pragma unroll
        for (int m = 0; m < 2; ++m) {
          int row = wr * 32 + m * 16 + l15;
          int s = (ks * 4 + l4) ^ (row & 7);
          af[m] = *reinterpret_cast<const bf16x8*>(&Als[row * 64 + s * 8]);
        }
#pragma unroll
        for (int n = 0; n < 4; ++n) {
          int col = wc * 64 + n * 16 + l15;
          int s = (ks * 4 + l4) ^ (col & 7);
          bfr[n] = *reinterpret_cast<const bf16x8*>(&Bls[col * 64 + s * 8]);
        }
#pragma unroll
        for (int m = 0; m < 2; ++m)
#pragma unroll
          for (int n = 0; n < 4; ++n)
            acc[m][n] = __builtin_amdgcn_mfma_f32_16x16x32_bf16(af[m], bfr[n], acc[m][n], 0, 0, 0);
      }
    }
  }

#pragma unroll
  for (int m = 0; m < 2; ++m)
#pragma unroll
    for (int n = 0; n < 4; ++n)
#pragma unroll
      for (int r = 0; r < 4; ++r)
        C[(size_t)(row0 + wr * 32 + m * 16 + l4 * 4 + r) * N + col0 + wc * 64 + n * 16 + l15] =
            acc[m][n][r];
}

// ---------------------------------------------------------------------------
// fp32 SGEMM (kept only for W' = Wg1 @ Wg2, K=64).
// ---------------------------------------------------------------------------
__global__ __launch_bounds__(256) void sgemm_f32(const float* __restrict__ A,
                                                 const float* __restrict__ B,
                                                 float* __restrict__ C,
                                                 int M, int N, int K) {
  __shared__ float As[8][128];
  __shared__ float Bs[8][128];
  const int tid = threadIdx.x;
  const int row0 = blockIdx.y * 128;
  const int col0 = blockIdx.x * 128;
  const int tm = (tid / 16) * 8;
  const int tn = (tid % 16) * 8;
  const int arow = tid >> 1;
  const int acol = (tid & 1) * 4;
  const int brow = tid >> 5;
  const int bcol = (tid & 31) * 4;

  float acc[8][8];
#pragma unroll
  for (int i = 0; i < 8; ++i)
#pragma unroll
    for (int j = 0; j < 8; ++j) acc[i][j] = 0.f;

  for (int k0 = 0; k0 < K; k0 += 8) {
    float4 av = make_float4(0.f, 0.f, 0.f, 0.f);
    if (row0 + arow < M) {
      int kb = k0 + acol;
      av = *reinterpret_cast<const float4*>(&A[(size_t)(row0 + arow) * K + kb]);
    }
    As[acol + 0][arow] = av.x;
    As[acol + 1][arow] = av.y;
    As[acol + 2][arow] = av.z;
    As[acol + 3][arow] = av.w;
    float4 bv = make_float4(0.f, 0.f, 0.f, 0.f);
    if (k0 + brow < K) {
      bv = *reinterpret_cast<const float4*>(&B[(size_t)(k0 + brow) * N + col0 + bcol]);
    }
    *reinterpret_cast<float4*>(&Bs[brow][bcol]) = bv;
    __syncthreads();
#pragma unroll
    for (int kk = 0; kk < 8; ++kk) {
      float a[8], b[8];
      *reinterpret_cast<float4*>(&a[0]) = *reinterpret_cast<const float4*>(&As[kk][tm]);
      *reinterpret_cast<float4*>(&a[4]) = *reinterpret_cast<const float4*>(&As[kk][tm + 4]);
      *reinterpret_cast<float4*>(&b[0]) = *reinterpret_cast<const float4*>(&Bs[kk][tn]);
      *reinterpret_cast<float4*>(&b[4]) = *reinterpret_cast<const float4*>(&Bs[kk][tn + 4]);
#pragma unroll
      for (int i = 0; i < 8; ++i)
#pragma unroll
        for (int j = 0; j < 8; ++j) acc[i][j] = fmaf(a[i], b[j], acc[i][j]);
    }
    __syncthreads();
  }
#pragma unroll
  for (int i = 0; i < 8; ++i) {
    int r = row0 + tm + i;
    if (r < M) {
#pragma unroll
      for (int j = 0; j < 8; ++j) {
        int c = col0 + tn + j;
        if (c < N) C[(size_t)r * N + c] = acc[i][j];
      }
    }
  }
}

// ---------------------------------------------------------------------------
// x fp32 -> xh, xl bf16 (hi/lo split), same layout.
// ---------------------------------------------------------------------------
__global__ __launch_bounds__(256) void repack_x_hl(const float* __restrict__ x,
                                                   unsigned short* __restrict__ xh,
                                                   unsigned short* __restrict__ xl) {
  int i = (blockIdx.x * 256 + threadIdx.x) * 4;
  float4 v = *reinterpret_cast<const float4*>(&x[i]);
  float f[4] = {v.x, v.y, v.z, v.w};
  unsigned short h[4], l[4];
#pragma unroll
  for (int j = 0; j < 4; ++j) {
    h[j] = f2bf(f[j]);
    l[j] = f2bf(f[j] - bf2f(h[j]));
  }
  *reinterpret_cast<ushort4*>(&xh[i]) = make_ushort4(h[0], h[1], h[2], h[3]);
  *reinterpret_cast<ushort4*>(&xl[i]) = make_ushort4(l[0], l[1], l[2], l[3]);
}

// ---------------------------------------------------------------------------
// W (rows x cols, fp32) -> W^T bf16 hi (and optional lo), (cols x rows).
// ---------------------------------------------------------------------------
__global__ __launch_bounds__(256) void repack_T(const float* __restrict__ W,
                                                unsigned short* __restrict__ hiT,
                                                unsigned short* __restrict__ loT,
                                                int rows, int cols, int has_lo) {
  __shared__ float t[64][65];
  const int k0 = blockIdx.y * 64, n0 = blockIdx.x * 64;
  const int tid = threadIdx.x;
  const int c = tid & 63, rr = tid >> 6;
#pragma unroll
  for (int r = 0; r < 16; ++r) {
    int kr = r * 4 + rr;
    t[kr][c] = W[(size_t)(k0 + kr) * cols + n0 + c];
  }
  __syncthreads();
#pragma unroll
  for (int r = 0; r < 16; ++r) {
    int n = r * 4 + rr;
    float f = t[c][n];
    unsigned short hb = f2bf(f);
    hiT[(size_t)(n0 + n) * rows + k0 + c] = hb;
    if (has_lo) loT[(size_t)(n0 + n) * rows + k0 + c] = f2bf(f - bf2f(hb));
  }
}

// ---------------------------------------------------------------------------
// RoPE applied in-place to q and k.
// ---------------------------------------------------------------------------
__global__ __launch_bounds__(256) void rope_qk(float* __restrict__ q, float* __restrict__ kk) {
  int idx = blockIdx.x * 256 + threadIdx.x;
  if (idx >= S_LEN * NH * (HD / 2)) return;
  int d = idx & 31;
  int sh = idx >> 5;
  int s = sh >> 5;
  float inv = 1.0f / powf(10000.0f, (float)d * (1.0f / 32.0f));
  float fr = (float)s * inv;
  float c = cosf(fr), sn = sinf(fr);
  size_t base = (size_t)sh * HD + d;
  float q1 = q[base], q2 = q[base + 32];
  q[base] = q1 * c - q2 * sn;
  q[base + 32] = q2 * c + q1 * sn;
  float k1 = kk[base], k2 = kk[base + 32];
  kk[base] = k1 * c - k2 * sn;
  kk[base + 32] = k2 * c + k1 * sn;
}

// ---------------------------------------------------------------------------
// Chunk means of k.
// ---------------------------------------------------------------------------
__global__ __launch_bounds__(256) void chunk_mean(const float* __restrict__ k,
                                                  float* __restrict__ kg) {
  int idx = blockIdx.x * 256 + threadIdx.x;
  if (idx >= NCH * NH * HD) return;
  int c = idx / (NH * HD);
  int hd = idx % (NH * HD);
  float sum = 0.f;
  for (int t = 0; t < CS; ++t) sum += k[(size_t)(c * CS + t) * (NH * HD) + hd];
  kg[idx] = sum * (1.0f / CS);
}

// ---------------------------------------------------------------------------
// Gate + top-3-past chunk selection (fp32 — selection must stay exact).
// ---------------------------------------------------------------------------
__global__ __launch_bounds__(256) void gate_topk(const float* __restrict__ q,
                                                 const float* __restrict__ kg,
                                                 int* __restrict__ amask) {
  int wid = threadIdx.x >> 6;
  int lane = threadIdx.x & 63;
  int s = blockIdx.x * 4 + wid;
  int h = blockIdx.y;
  int myc = s >> 8;
  float qd = q[((size_t)s * NH + h) * HD + lane];
  float g[NCH];
#pragma unroll
  for (int c = 0; c < NCH; ++c) {
    float p = qd * kg[((size_t)c * NH + h) * HD + lane];
#pragma unroll
    for (int off = 32; off; off >>= 1) p += __shfl_xor(p, off);
    g[c] = p;
  }
  int chosen = 0;
#pragma unroll
  for (int pick = 0; pick < 3; ++pick) {
    float best = -INFINITY;
    int bi = -1;
#pragma unroll
    for (int c = 0; c < NCH; ++c) {
      if (c < myc && !((chosen >> c) & 1) && g[c] > best) {
        best = g[c];
        bi = c;
      }
    }
    if (bi >= 0) chosen |= (1 << bi);
  }
  int mask = chosen | (1 << myc);
  if (lane == 0) amask[h * S_LEN + s] = mask;
}

// ---------------------------------------------------------------------------
// K fp32 [s][h][d] -> fragment-major bf16: khf[h][tile][frag=st*2+half][lane][8]
// so attention's LOADK is 8 wave-contiguous dwordx4 loads (no address
// divergence). LDS-staged for coalesced reads.
// ---------------------------------------------------------------------------
__global__ __launch_bounds__(256) void repack_kf(const float* __restrict__ k,
                                                 unsigned short* __restrict__ khf) {
  __shared__ float tl[64][68];
  const int t = blockIdx.x;   // 64-key tile
  const int h = blockIdx.y;
  const int tid = threadIdx.x;
  const int t0 = t * 64;
  {
    const int r = tid >> 2, c4 = (tid & 3) * 16;
    const float* src = &k[((size_t)(t0 + r) * NH + h) * HD + c4];
#pragma unroll
    for (int qd = 0; qd < 4; ++qd)
      *reinterpret_cast<float4*>(&tl[r][c4 + qd * 4]) =
          *reinterpret_cast<const float4*>(src + qd * 4);
  }
  __syncthreads();
  const int w = tid >> 6, l = tid & 63;
  const int l15 = l & 15, g = l >> 4;
  unsigned short* ob = khf + (((size_t)h * 32 + t) * 8) * 512;
#pragma unroll
  for (int ff = 0; ff < 2; ++ff) {
    const int f = 2 * w + ff;
    const int st = f >> 1, half = f & 1;
    const float* rp = &tl[st * 16 + l15][g * 8 + half * 32];
    ushort4 u0 = make_ushort4(f2bf(rp[0]), f2bf(rp[1]), f2bf(rp[2]), f2bf(rp[3]));
    ushort4 u1 = make_ushort4(f2bf(rp[4]), f2bf(rp[5]), f2bf(rp[6]), f2bf(rp[7]));
    *reinterpret_cast<ushort4*>(ob + (size_t)f * 512 + l * 8) = u0;
    *reinterpret_cast<ushort4*>(ob + (size_t)f * 512 + l * 8 + 4) = u1;
  }
}

// ---------------------------------------------------------------------------
// V fp32 [s][h][d] -> fragment-major bf16: vhf[h][tile][fp=st*2+p][lane][8]
// where lane's 8 elems pack (vb[st][2p], vb[st][2p+1]):
//   e in [0,8): cb = 2p + (e>>2), j = e&3, value = V[t0+st*16+4g+j][h][cb*16+l15]
// ---------------------------------------------------------------------------
__global__ __launch_bounds__(256) void repack_vf(const float* __restrict__ v,
                                                 unsigned short* __restrict__ vhf) {
  __shared__ float tl[64][68];
  const int t = blockIdx.x;
  const int h = blockIdx.y;
  const int tid = threadIdx.x;
  const int t0 = t * 64;
  {
    const int r = tid >> 2, c4 = (tid & 3) * 16;
    const float* src = &v[((size_t)(t0 + r) * NH + h) * HD + c4];
#pragma unroll
    for (int qd = 0; qd < 4; ++qd)
      *reinterpret_cast<float4*>(&tl[r][c4 + qd * 4]) =
          *reinterpret_cast<const float4*>(src + qd * 4);
  }
  __syncthreads();
  const int w = tid >> 6, l = tid & 63;
  const int l15 = l & 15, g = l >> 4;
  unsigned short* ob = vhf + (((size_t)h * 32 + t) * 8) * 512;
#pragma unroll
  for (int ff = 0; ff < 2; ++ff) {
    const int fp = 2 * w + ff;
    const int st = fp >> 1, p = fp & 1;
    unsigned short u[8];
#pragma unroll
    for (int e = 0; e < 8; ++e) {
      const int cb = 2 * p + (e >> 2);
      const int j = e & 3;
      u[e] = f2bf(tl[st * 16 + 4 * g + j][cb * 16 + l15]);
    }
    *reinterpret_cast<ushort4*>(ob + (size_t)fp * 512 + l * 8) =
        make_ushort4(u[0], u[1], u[2], u[3]);
    *reinterpret_cast<ushort4*>(ob + (size_t)fp * 512 + l * 8 + 4) =
        make_ushort4(u[4], u[5], u[6], u[7]);
  }
}

// ---------------------------------------------------------------------------
// MFMA flash attention, split-K across 4 waves (R9 structure), with
// fragment-major K/V loads: per tile, 8+8 wave-contiguous dwordx4 loads
// replace 24 address-divergent loads. Numerics identical to R9.
// ---------------------------------------------------------------------------
__global__ __launch_bounds__(256) void attn_mfma(const float* __restrict__ q,
                                                 const unsigned short* __restrict__ khf,
                                                 const unsigned short* __restrict__ vhf,
                                                 const int* __restrict__ amask,
                                                 float* __restrict__ o) {
  const int B = blockIdx.x;
  const int xcd = B & 7;
  const int jb = B >> 3;
  const int h = xcd + ((jb >> 7) << 3);
  const int s0 = (jb & 127) << 4;
  const int tid = threadIdx.x;
  const int wid = tid >> 6;
  const int lane = tid & 63;
  const int l15 = lane & 15, g = lane >> 4;
  const int myS = s0 + l15;
  const int myc = s0 >> 8;
  const int ktm = (s0 & (CS - 1)) >> 6;

  __shared__ float lm[4][16];
  __shared__ float ll[4][16];
  __shared__ float lacc[4][16][64];

  // Q B-frag, scale 1/8 folded (exact for pow2)
  const float* qrow = q + ((size_t)myS * NH + h) * HD;
  bf16x8 qf[2];
#pragma unroll
  for (int hf = 0; hf < 2; ++hf)
#pragma unroll
    for (int jj = 0; jj < 8; ++jj)
      qf[hf][jj] = (short)f2bf(qrow[hf * 32 + g * 8 + jj] * 0.125f);

  int mymask = amask[h * S_LEN + myS];
  int wmask = mymask;
  wmask |= __shfl_xor(wmask, 1);
  wmask |= __shfl_xor(wmask, 2);
  wmask |= __shfl_xor(wmask, 4);
  wmask |= __shfl_xor(wmask, 8);
  const int pmask = wmask & ~(1 << myc);
  const int ntot = (ktm + 1) + 4 * __popc(pmask);

  // j -> (t0 | lane_on<<16). Self-chunk tiles first, then past chunks.
  auto DEC = [&](int j) -> int {
    if (j <= ktm) return ((s0 & ~255) + (j << 6)) | (1 << 16);
    int jj = j - ktm - 1;
    int mm = pmask;
    int drop = jj >> 2;
    for (int b = 0; b < drop; ++b) mm &= mm - 1;
    int c = __ffs(mm) - 1;
    return ((c << 8) + ((jj & 3) << 6)) | (((mymask >> c) & 1) << 16);
  };

  const unsigned short* khh = khf + (((size_t)h * 32) << 12);
  const unsigned short* vhh = vhf + (((size_t)h * 32) << 12);

  bf16x8 kr[4][2];
  auto LOADK = [&](int t0) {
    const unsigned short* tb = khh + ((size_t)(t0 >> 6) << 12) + lane * 8;
#pragma unroll
    for (int f = 0; f < 8; ++f)
      kr[f >> 1][f & 1] = *reinterpret_cast<const bf16x8*>(tb + f * 512);
  };

  float m = -1e30f, lsum = 0.f;
  f32x4 accv[4];
#pragma unroll
  for (int i = 0; i < 4; ++i) accv[i] = (f32x4){0.f, 0.f, 0.f, 0.f};

  if (wid < ntot) LOADK(DEC(wid) & 0xFFFF);

#pragma unroll
  for (int i = 0; i < 8; ++i) {
    const int j = wid + (i << 2);
    if (j < ntot) {
      const int ent = DEC(j);
      const int t0 = ent & 0xFFFF;
      const bool lane_on = (ent >> 16) != 0;
      const bool diag = (j == ktm);

      // V fragments (wave-contiguous; issued early, consumed after softmax)
      const unsigned short* vtb = vhh + ((size_t)(t0 >> 6) << 12) + lane * 8;
      bf16x4 vb[4][4];
#pragma unroll
      for (int fp = 0; fp < 8; ++fp) {
        bf16x8 wv = *reinterpret_cast<const bf16x8*>(vtb + fp * 512);
        const int st = fp >> 1, pp = fp & 1;
#pragma unroll
        for (int jj = 0; jj < 4; ++jj) {
          vb[st][2 * pp][jj] = wv[jj];
          vb[st][2 * pp + 1][jj] = wv[4 + jj];
        }
      }

      // QK^T (scale pre-folded into qf)
      float p[16];
      __builtin_amdgcn_s_setprio(1);
#pragma unroll
      for (int st = 0; st < 4; ++st) {
        f32x4 d = (f32x4){0.f, 0.f, 0.f, 0.f};
        d = __builtin_amdgcn_mfma_f32_16x16x32_bf16(kr[st][0], qf[0], d, 0, 0, 0);
        d = __builtin_amdgcn_mfma_f32_16x16x32_bf16(kr[st][1], qf[1], d, 0, 0, 0);
#pragma unroll
        for (int r = 0; r < 4; ++r) {
          bool ok = lane_on && (!diag || (t0 + st * 16 + 4 * g + r <= myS));
          p[st * 4 + r] = ok ? d[r] : -1e30f;
        }
      }
      __builtin_amdgcn_s_setprio(0);

      // Prefetch next tile's K into the same regs (WAR-ordered)
      if (j + 4 < ntot) LOADK(DEC(j + 4) & 0xFFFF);

      // Row max (4-lane groups share a row via xor 16/32)
      float mt = -1e30f;
#pragma unroll
      for (int ii = 0; ii < 16; ++ii) mt = fmaxf(mt, p[ii]);
      mt = fmaxf(mt, __shfl_xor(mt, 16));
      mt = fmaxf(mt, __shfl_xor(mt, 32));

      const float mnew = fmaxf(m, mt);
      const float corr = __expf(m - mnew);
      float ps = 0.f;
#pragma unroll
      for (int ii = 0; ii < 16; ++ii) {
        float pv = (p[ii] > -1e29f) ? __expf(p[ii] - mnew) : 0.f;
        p[ii] = pv;
        ps += pv;
      }
      ps += __shfl_xor(ps, 16);
      ps += __shfl_xor(ps, 32);
      lsum = lsum * corr + ps;
      m = mnew;

      // Rescale accumulator (acc rows are q-rows 4g+r; corr lives at lane 4g+r)
#pragma unroll
      for (int r = 0; r < 4; ++r) {
        float cr = __shfl(corr, 4 * g + r);
#pragma unroll
        for (int cb = 0; cb < 4; ++cb) accv[cb][r] *= cr;
      }

      // PV: P fragment (A of 16x16x16) is exactly the S^T output fragment
      __builtin_amdgcn_s_setprio(1);
#pragma unroll
      for (int st = 0; st < 4; ++st) {
        bf16x4 pa;
#pragma unroll
        for (int jj = 0; jj < 4; ++jj) pa[jj] = (short)f2bf(p[st * 4 + jj]);
#pragma unroll
        for (int cb = 0; cb < 4; ++cb)
          accv[cb] = mfma16(pa, vb[st][cb], accv[cb]);
      }
      __builtin_amdgcn_s_setprio(0);
    }
  }

  // ---- store partials to LDS ----
#pragma unroll
  for (int cb = 0; cb < 4; ++cb)
#pragma unroll
    for (int r = 0; r < 4; ++r) lacc[wid][cb * 4 + r][lane] = accv[cb][r];
  if (lane < 16) {
    lm[wid][lane] = m;
    ll[wid][lane] = lsum;
  }
  __syncthreads();

  // ---- merge: wave `wid` produces dim-block cb = wid ----
  float outv[4];
#pragma unroll
  for (int r = 0; r < 4; ++r) {
    const int row = 4 * g + r;
    float m0 = lm[0][row], m1 = lm[1][row], m2 = lm[2][row], m3 = lm[3][row];
    float mt = fmaxf(fmaxf(m0, m1), fmaxf(m2, m3));
    float e0 = __expf(m0 - mt), e1 = __expf(m1 - mt);
    float e2 = __expf(m2 - mt), e3 = __expf(m3 - mt);
    float ltot = ll[0][row] * e0 + ll[1][row] * e1 + ll[2][row] * e2 + ll[3][row] * e3;
    float a = lacc[0][wid * 4 + r][lane] * e0 + lacc[1][wid * 4 + r][lane] * e1 +
              lacc[2][wid * 4 + r][lane] * e2 + lacc[3][wid * 4 + r][lane] * e3;
    outv[r] = a / ltot;
  }
#pragma unroll
  for (int r = 0; r < 4; ++r)
    o[((size_t)(s0 + 4 * g + r) * NH + h) * HD + wid * 16 + l15] = outv[r];
}

// ---------------------------------------------------------------------------
// RMS-norm + sigmoid gate; emits bf16 for the out-proj A-operand.
// ---------------------------------------------------------------------------
__global__ __launch_bounds__(256) void postproc(const float* __restrict__ o,
                                                const float* __restrict__ g,
                                                const float* __restrict__ w,
                                                unsigned short* __restrict__ o2h) {
  int idx = blockIdx.x * 256 + threadIdx.x;
  int lane = threadIdx.x & 63;
  float val = o[idx];
  float ss = val * val;
#pragma unroll
  for (int off = 32; off; off >>= 1) ss += __shfl_xor(ss, off);
  float r = rsqrtf(ss * (1.0f / HD) + 1e-6f);
  float gv = g[idx];
  float sig = 1.0f / (1.0f + expf(-gv));
  o2h[idx] = f2bf(val * r * w[lane] * sig);
}

// ---------------------------------------------------------------------------
extern "C" void kernel_launch(void* const* d_in, const int* in_sizes, int n_in,
                              void* d_out, int out_size, void* d_ws, size_t ws_size,
                              hipStream_t stream) {
  const float* x   = (const float*)d_in[0];
  const float* Wq  = (const float*)d_in[1];
  const float* Wk  = (const float*)d_in[2];
  const float* Wv  = (const float*)d_in[3];
  const float* Wo  = (const float*)d_in[4];
  const float* Wg1 = (const float*)d_in[5];
  const float* Wg2 = (const float*)d_in[6];
  const float* onw = (const float*)d_in[7];
  float* out = (float*)d_out;

  const size_t BIG = (size_t)S_LEN * D_DIM;  // 4M elements
  float* q    = (float*)d_ws;
  float* k    = q + BIG;
  float* v    = k + BIG;
  float* o    = v + BIG;
  float* gbuf = o + BIG;
  float* kg   = gbuf + BIG;                    // NCH*NH*HD
  int* amask  = (int*)(kg + NCH * NH * HD);    // NH*S
  unsigned short* xh  = (unsigned short*)(amask + NH * S_LEN);
  unsigned short* xl  = xh + BIG;
  unsigned short* whq = xl + BIG;
  unsigned short* wlq = whq + BIG;
  unsigned short* whk = wlq + BIG;
  unsigned short* wlk = whk + BIG;
  unsigned short* whv = wlk + BIG;
  unsigned short* whg = whv + BIG;
  unsigned short* khf = whg + BIG;
  unsigned short* vhf = khf + BIG;
  unsigned short* o2h = vhf + BIG;

  const dim3 gT(32, 32);
  // Split x into hi/lo bf16
  repack_x_hl<<<(int)(BIG / 4 / 256), 256, 0, stream>>>(x, xh, xl);
  // Weight repacks
  repack_T<<<gT, 256, 0, stream>>>(Wq, whq, wlq, D_DIM, D_DIM, 1);
  repack_T<<<gT, 256, 0, stream>>>(Wk, whk, wlk, D_DIM, D_DIM, 1);
  repack_T<<<gT, 256, 0, stream>>>(Wv, whv, nullptr, D_DIM, D_DIM, 0);
  // W' = Wg1 @ Wg2 (fp32, K=64) into o; repack to whg
  sgemm_f32<<<dim3(16, 16), 256, 0, stream>>>(Wg1, Wg2, o, D_DIM, D_DIM, HD);
  repack_T<<<gT, 256, 0, stream>>>(o, whg, nullptr, D_DIM, D_DIM, 0);

  // Fused Q(3) K(3) V(1) G(1) projections — one launch, 2048 blocks
  {
    QKVG gg;
    gg.xh = xh; gg.xl = xl;
    gg.wh[0] = whq; gg.wh[1] = whk; gg.wh[2] = whv; gg.wh[3] = whg;
    gg.wl[0] = wlq; gg.wl[1] = wlk; gg.wl[2] = nullptr; gg.wl[3] = nullptr;
    gg.C[0] = q; gg.C[1] = k; gg.C[2] = v; gg.C[3] = gbuf;
    gg.np[0] = 3; gg.np[1] = 3; gg.np[2] = 1; gg.np[3] = 1;
    gemm_qkvg<<<2048, 256, 0, stream>>>(gg);
  }

  // RoPE
  rope_qk<<<S_LEN * NH * (HD / 2) / 256, 256, 0, stream>>>(q, k);
  // Chunk means + gating (fp32)
  chunk_mean<<<(NCH * NH * HD + 255) / 256, 256, 0, stream>>>(k, kg);
  gate_topk<<<dim3(S_LEN / 4, NH), 256, 0, stream>>>(q, kg, amask);
  // Fragment-major repacks for attention
  repack_kf<<<dim3(S_LEN / 64, NH), 256, 0, stream>>>(k, khf);
  repack_vf<<<dim3(S_LEN / 64, NH), 256, 0, stream>>>(v, vhf);
  // Attention (overwrites o): 4-wave split-K, head-locality XCD swizzle
  attn_mfma<<<(S_LEN / 16) * NH, 256, 0, stream>>>(q, khf, vhf, amask, o);
  // RMS-norm + sigmoid gate -> bf16
  postproc<<<(int)(BIG / 256), 256, 0, stream>>>(o, gbuf, onw, o2h);
  // out = o2 @ Wo (1-pass bf16); reuse whq for Wo^T
  repack_T<<<gT, 256, 0, stream>>>(Wo, whq, nullptr, D_DIM, D_DIM, 0);
  {
    G3 g3{{o2h, o2h, o2h}, {whq, whq, whq}, 1};
    gemm_bt<<<(S_LEN / 64) * (D_DIM / 128), 256, 0, stream>>>(g3, out, S_LEN, D_DIM, D_DIM);
  }
}

// Round 12
// 370.478 us; speedup vs baseline: 1.8115x; 1.2928x over previous
//
#include <hip/hip_runtime.h>
#include <hip/hip_bf16.h>
#include <math.h>

#define S_LEN 2048
#define D_DIM 2048
#define NH 32
#define HD 64
#define CS 256
#define NCH 8

typedef __attribute__((ext_vector_type(8))) short bf16x8;
typedef __attribute__((ext_vector_type(4))) short bf16x4;
typedef __attribute__((ext_vector_type(4))) float f32x4;

__device__ __forceinline__ unsigned short f2bf(float f) {
  unsigned int u = __builtin_bit_cast(unsigned int, f);
  unsigned int r = (u + 0x7fffu + ((u >> 16) & 1u)) >> 16;
  return (unsigned short)r;
}
__device__ __forceinline__ float bf2f(unsigned short b) {
  unsigned int u = ((unsigned int)b) << 16;
  return __builtin_bit_cast(float, u);
}

__device__ __forceinline__ f32x4 mfma16(bf16x4 a, bf16x4 b, f32x4 c) {
#if __has_builtin(__builtin_amdgcn_mfma_f32_16x16x16_bf16)
  return __builtin_amdgcn_mfma_f32_16x16x16_bf16(a, b, c, 0, 0, 0);
#elif __has_builtin(__builtin_amdgcn_mfma_f32_16x16x16bf16_1k)
  return __builtin_amdgcn_mfma_f32_16x16x16bf16_1k(a, b, c, 0, 0, 0);
#else
  asm("v_mfma_f32_16x16x16_bf16 %0, %1, %2, %0" : "+v"(c) : "v"(a), "v"(b));
  return c;
#endif
}

__device__ __forceinline__ void gload16(const void* gp, void* lp) {
  __builtin_amdgcn_global_load_lds(
      (const __attribute__((address_space(1))) unsigned int*)gp,
      (__attribute__((address_space(3))) unsigned int*)lp, 16, 0, 0);
}

// ---------------------------------------------------------------------------
// Fused QKVG GEMM, 128x128 tile (4 waves x 64x64), BK=64, 32KB LDS.
// Grid = 4 outputs x 256 blocks = 1024. Balanced XCD decode:
//   xcd = bid&7, local = bid>>3 (0..127), c = local>>6, idx = local&63
//   out = (xcd&1) + 2*c   -> even XCDs run {Q,V}, odd run {K,G}: 4 pass-units each
//   grp = xcd>>1          -> col-group of 4 panels (2MB B working set per L2)
//   row0 = (idx>>2)*128 (rows inner), col0 = (grp*4 + (idx&3))*128
// ---------------------------------------------------------------------------
struct QKVG {
  const unsigned short* xh;
  const unsigned short* xl;
  const unsigned short* wh[4];
  const unsigned short* wl[4];
  float* C[4];
  int np[4];
};

__global__ __launch_bounds__(256) void gemm_qkvg(QKVG g) {
  __shared__ __align__(16) unsigned short Als[128 * 64];
  __shared__ __align__(16) unsigned short Bls[128 * 64];
  const int tid = threadIdx.x;
  const int wid = tid >> 6, lane = tid & 63;
  const int l15 = lane & 15, l4 = lane >> 4;
  const int wr = wid >> 1, wc = wid & 1;
  const int K = D_DIM, N = D_DIM;

  const int bid = blockIdx.x;
  const int xcd = bid & 7;
  const int local = bid >> 3;     // 0..127
  const int c = local >> 6;       // 0,1
  const int idx = local & 63;
  const int out = (xcd & 1) + 2 * c;
  const int grp = xcd >> 1;
  const int row0 = (idx >> 2) << 7;                // 16 row-tiles, inner
  const int col0 = ((grp << 2) + (idx & 3)) << 7;  // 16 col-tiles

  f32x4 acc[4][4];
#pragma unroll
  for (int m = 0; m < 4; ++m)
#pragma unroll
    for (int n = 0; n < 4; ++n) acc[m][n] = (f32x4){0.f, 0.f, 0.f, 0.f};

  const int np = g.np[out];
  for (int p = 0; p < np; ++p) {
    const unsigned short* Ap = (p == 2) ? g.xl : g.xh;
    const unsigned short* Bp = (p == 1) ? g.wl[out] : g.wh[out];
    for (int kt = 0; kt < K; kt += 64) {
      __syncthreads();
#pragma unroll
      for (int i = 0; i < 4; ++i) {
        const int Lb = i * 4096 + wid * 1024;
        const int L = Lb + lane * 16;
        const int row = L >> 7;
        const int s = (L >> 4) & 7;
        const int cofs = (s ^ (row & 7)) << 3;
        gload16(Ap + (size_t)(row0 + row) * K + kt + cofs, (char*)Als + Lb);
        gload16(Bp + (size_t)(col0 + row) * K + kt + cofs, (char*)Bls + Lb);
      }
      asm volatile("s_waitcnt vmcnt(0)" ::: "memory");
      __syncthreads();
#pragma unroll
      for (int ks = 0; ks < 2; ++ks) {
        bf16x8 af[4], bfr[4];
#pragma unroll
        for (int m = 0; m < 4; ++m) {
          int row = wr * 64 + m * 16 + l15;
          int s = (ks * 4 + l4) ^ (row & 7);
          af[m] = *reinterpret_cast<const bf16x8*>(&Als[row * 64 + s * 8]);
        }
#pragma unroll
        for (int n = 0; n < 4; ++n) {
          int col = wc * 64 + n * 16 + l15;
          int s = (ks * 4 + l4) ^ (col & 7);
          bfr[n] = *reinterpret_cast<const bf16x8*>(&Bls[col * 64 + s * 8]);
        }
#pragma unroll
        for (int m = 0; m < 4; ++m)
#pragma unroll
          for (int n = 0; n < 4; ++n)
            acc[m][n] = __builtin_amdgcn_mfma_f32_16x16x32_bf16(af[m], bfr[n], acc[m][n], 0, 0, 0);
      }
    }
  }

  float* C = g.C[out];
#pragma unroll
  for (int m = 0; m < 4; ++m)
#pragma unroll
    for (int n = 0; n < 4; ++n)
#pragma unroll
      for (int r = 0; r < 4; ++r)
        C[(size_t)(row0 + wr * 64 + m * 16 + l4 * 4 + r) * N + col0 + wc * 64 + n * 16 + l15] =
            acc[m][n][r];
}

// ---------------------------------------------------------------------------
// bf16 MFMA GEMM 64x128 (kept for the out-projection: 512 blocks -> 2/CU).
// ---------------------------------------------------------------------------
struct G3 {
  const unsigned short* A[3];
  const unsigned short* B[3];
  int np;
};

__global__ __launch_bounds__(256) void gemm_bt(G3 g, float* __restrict__ C,
                                               int M, int N, int K) {
  __shared__ __align__(16) unsigned short Als[64 * 64];
  __shared__ __align__(16) unsigned short Bls[128 * 64];
  const int tid = threadIdx.x;
  const int wid = tid >> 6, lane = tid & 63;
  const int l15 = lane & 15, l4 = lane >> 4;
  const int wr = wid >> 1, wc = wid & 1;
  const int nbx = N >> 7;
  int bid = blockIdx.x;
  const int nwg = gridDim.x;
  if ((nwg & 7) == 0) {
    int q = nwg >> 3;
    bid = (bid & 7) * q + (bid >> 3);
  }
  const int row0 = (bid / nbx) << 6;
  const int col0 = (bid % nbx) << 7;

  f32x4 acc[2][4];
#pragma unroll
  for (int m = 0; m < 2; ++m)
#pragma unroll
    for (int n = 0; n < 4; ++n) acc[m][n] = (f32x4){0.f, 0.f, 0.f, 0.f};

  for (int p = 0; p < g.np; ++p) {
    const unsigned short* Ap = g.A[p];
    const unsigned short* Bp = g.B[p];
    for (int kt = 0; kt < K; kt += 64) {
      __syncthreads();
#pragma unroll
      for (int i = 0; i < 2; ++i) {
        const int Lb = i * 4096 + wid * 1024;
        const int L = Lb + lane * 16;
        const int row = L >> 7;
        const int s = (L >> 4) & 7;
        const int cofs = (s ^ (row & 7)) << 3;
        gload16(Ap + (size_t)(row0 + row) * K + kt + cofs, (char*)Als + Lb);
      }
#pragma unroll
      for (int i = 0; i < 4; ++i) {
        const int Lb = i * 4096 + wid * 1024;
        const int L = Lb + lane * 16;
        const int row = L >> 7;
        const int s = (L >> 4) & 7;
        const int cofs = (s ^ (row & 7)) << 3;
        gload16(Bp + (size_t)(col0 + row) * K + kt + cofs, (char*)Bls + Lb);
      }
      asm volatile("s_waitcnt vmcnt(0)" ::: "memory");
      __syncthreads();
#pragma unroll
      for (int ks = 0; ks < 2; ++ks) {
        bf16x8 af[2], bfr[4];
#pragma unroll
        for (int m = 0; m < 2; ++m) {
          int row = wr * 32 + m * 16 + l15;
          int s = (ks * 4 + l4) ^ (row & 7);
          af[m] = *reinterpret_cast<const bf16x8*>(&Als[row * 64 + s * 8]);
        }
#pragma unroll
        for (int n = 0; n < 4; ++n) {
          int col = wc * 64 + n * 16 + l15;
          int s = (ks * 4 + l4) ^ (col & 7);
          bfr[n] = *reinterpret_cast<const bf16x8*>(&Bls[col * 64 + s * 8]);
        }
#pragma unroll
        for (int m = 0; m < 2; ++m)
#pragma unroll
          for (int n = 0; n < 4; ++n)
            acc[m][n] = __builtin_amdgcn_mfma_f32_16x16x32_bf16(af[m], bfr[n], acc[m][n], 0, 0, 0);
      }
    }
  }

#pragma unroll
  for (int m = 0; m < 2; ++m)
#pragma unroll
    for (int n = 0; n < 4; ++n)
#pragma unroll
      for (int r = 0; r < 4; ++r)
        C[(size_t)(row0 + wr * 32 + m * 16 + l4 * 4 + r) * N + col0 + wc * 64 + n * 16 + l15] =
            acc[m][n][r];
}

// ---------------------------------------------------------------------------
// fp32 SGEMM (kept only for W' = Wg1 @ Wg2, K=64).
// ---------------------------------------------------------------------------
__global__ __launch_bounds__(256) void sgemm_f32(const float* __restrict__ A,
                                                 const float* __restrict__ B,
                                                 float* __restrict__ C,
                                                 int M, int N, int K) {
  __shared__ float As[8][128];
  __shared__ float Bs[8][128];
  const int tid = threadIdx.x;
  const int row0 = blockIdx.y * 128;
  const int col0 = blockIdx.x * 128;
  const int tm = (tid / 16) * 8;
  const int tn = (tid % 16) * 8;
  const int arow = tid >> 1;
  const int acol = (tid & 1) * 4;
  const int brow = tid >> 5;
  const int bcol = (tid & 31) * 4;

  float acc[8][8];
#pragma unroll
  for (int i = 0; i < 8; ++i)
#pragma unroll
    for (int j = 0; j < 8; ++j) acc[i][j] = 0.f;

  for (int k0 = 0; k0 < K; k0 += 8) {
    float4 av = make_float4(0.f, 0.f, 0.f, 0.f);
    if (row0 + arow < M) {
      int kb = k0 + acol;
      av = *reinterpret_cast<const float4*>(&A[(size_t)(row0 + arow) * K + kb]);
    }
    As[acol + 0][arow] = av.x;
    As[acol + 1][arow] = av.y;
    As[acol + 2][arow] = av.z;
    As[acol + 3][arow] = av.w;
    float4 bv = make_float4(0.f, 0.f, 0.f, 0.f);
    if (k0 + brow < K) {
      bv = *reinterpret_cast<const float4*>(&B[(size_t)(k0 + brow) * N + col0 + bcol]);
    }
    *reinterpret_cast<float4*>(&Bs[brow][bcol]) = bv;
    __syncthreads();
#pragma unroll
    for (int kk = 0; kk < 8; ++kk) {
      float a[8], b[8];
      *reinterpret_cast<float4*>(&a[0]) = *reinterpret_cast<const float4*>(&As[kk][tm]);
      *reinterpret_cast<float4*>(&a[4]) = *reinterpret_cast<const float4*>(&As[kk][tm + 4]);
      *reinterpret_cast<float4*>(&b[0]) = *reinterpret_cast<const float4*>(&Bs[kk][tn]);
      *reinterpret_cast<float4*>(&b[4]) = *reinterpret_cast<const float4*>(&Bs[kk][tn + 4]);
#pragma unroll
      for (int i = 0; i < 8; ++i)
#pragma unroll
        for (int j = 0; j < 8; ++j) acc[i][j] = fmaf(a[i], b[j], acc[i][j]);
    }
    __syncthreads();
  }
#pragma unroll
  for (int i = 0; i < 8; ++i) {
    int r = row0 + tm + i;
    if (r < M) {
#pragma unroll
      for (int j = 0; j < 8; ++j) {
        int c = col0 + tn + j;
        if (c < N) C[(size_t)r * N + c] = acc[i][j];
      }
    }
  }
}

// ---------------------------------------------------------------------------
// x fp32 -> xh, xl bf16 (hi/lo split), same layout.
// ---------------------------------------------------------------------------
__global__ __launch_bounds__(256) void repack_x_hl(const float* __restrict__ x,
                                                   unsigned short* __restrict__ xh,
                                                   unsigned short* __restrict__ xl) {
  int i = (blockIdx.x * 256 + threadIdx.x) * 4;
  float4 v = *reinterpret_cast<const float4*>(&x[i]);
  float f[4] = {v.x, v.y, v.z, v.w};
  unsigned short h[4], l[4];
#pragma unroll
  for (int j = 0; j < 4; ++j) {
    h[j] = f2bf(f[j]);
    l[j] = f2bf(f[j] - bf2f(h[j]));
  }
  *reinterpret_cast<ushort4*>(&xh[i]) = make_ushort4(h[0], h[1], h[2], h[3]);
  *reinterpret_cast<ushort4*>(&xl[i]) = make_ushort4(l[0], l[1], l[2], l[3]);
}

// ---------------------------------------------------------------------------
// W (rows x cols, fp32) -> W^T bf16 hi (and optional lo), (cols x rows).
// Single-weight version (W' -> whg, Wo -> whq).
// ---------------------------------------------------------------------------
__global__ __launch_bounds__(256) void repack_T(const float* __restrict__ W,
                                                unsigned short* __restrict__ hiT,
                                                unsigned short* __restrict__ loT,
                                                int rows, int cols, int has_lo) {
  __shared__ float t[64][65];
  const int k0 = blockIdx.y * 64, n0 = blockIdx.x * 64;
  const int tid = threadIdx.x;
  const int c = tid & 63, rr = tid >> 6;
#pragma unroll
  for (int r = 0; r < 16; ++r) {
    int kr = r * 4 + rr;
    t[kr][c] = W[(size_t)(k0 + kr) * cols + n0 + c];
  }
  __syncthreads();
#pragma unroll
  for (int r = 0; r < 16; ++r) {
    int n = r * 4 + rr;
    float f = t[c][n];
    unsigned short hb = f2bf(f);
    hiT[(size_t)(n0 + n) * rows + k0 + c] = hb;
    if (has_lo) loT[(size_t)(n0 + n) * rows + k0 + c] = f2bf(f - bf2f(hb));
  }
}

// ---------------------------------------------------------------------------
// Fused 3-weight transpose repack (Wq, Wk with lo; Wv hi-only). Grid z picks W.
// ---------------------------------------------------------------------------
struct RT3 {
  const float* W[3];
  unsigned short* hiT[3];
  unsigned short* loT[3];
  int has_lo[3];
};

__global__ __launch_bounds__(256) void repack_T3(RT3 a) {
  __shared__ float t[64][65];
  const int wsel = blockIdx.z;
  const float* W = a.W[wsel];
  unsigned short* hiT = a.hiT[wsel];
  unsigned short* loT = a.loT[wsel];
  const int has_lo = a.has_lo[wsel];
  const int k0 = blockIdx.y * 64, n0 = blockIdx.x * 64;
  const int tid = threadIdx.x;
  const int c = tid & 63, rr = tid >> 6;
#pragma unroll
  for (int r = 0; r < 16; ++r) {
    int kr = r * 4 + rr;
    t[kr][c] = W[(size_t)(k0 + kr) * D_DIM + n0 + c];
  }
  __syncthreads();
#pragma unroll
  for (int r = 0; r < 16; ++r) {
    int n = r * 4 + rr;
    float f = t[c][n];
    unsigned short hb = f2bf(f);
    hiT[(size_t)(n0 + n) * D_DIM + k0 + c] = hb;
    if (has_lo) loT[(size_t)(n0 + n) * D_DIM + k0 + c] = f2bf(f - bf2f(hb));
  }
}

// ---------------------------------------------------------------------------
// RoPE applied in-place to q and k.
// ---------------------------------------------------------------------------
__global__ __launch_bounds__(256) void rope_qk(float* __restrict__ q, float* __restrict__ kk) {
  int idx = blockIdx.x * 256 + threadIdx.x;
  if (idx >= S_LEN * NH * (HD / 2)) return;
  int d = idx & 31;
  int sh = idx >> 5;
  int s = sh >> 5;
  float inv = 1.0f / powf(10000.0f, (float)d * (1.0f / 32.0f));
  float fr = (float)s * inv;
  float c = cosf(fr), sn = sinf(fr);
  size_t base = (size_t)sh * HD + d;
  float q1 = q[base], q2 = q[base + 32];
  q[base] = q1 * c - q2 * sn;
  q[base + 32] = q2 * c + q1 * sn;
  float k1 = kk[base], k2 = kk[base + 32];
  kk[base] = k1 * c - k2 * sn;
  kk[base + 32] = k2 * c + k1 * sn;
}

// ---------------------------------------------------------------------------
// Chunk means of k.
// ---------------------------------------------------------------------------
__global__ __launch_bounds__(256) void chunk_mean(const float* __restrict__ k,
                                                  float* __restrict__ kg) {
  int idx = blockIdx.x * 256 + threadIdx.x;
  if (idx >= NCH * NH * HD) return;
  int c = idx / (NH * HD);
  int hd = idx % (NH * HD);
  float sum = 0.f;
  for (int t = 0; t < CS; ++t) sum += k[(size_t)(c * CS + t) * (NH * HD) + hd];
  kg[idx] = sum * (1.0f / CS);
}

// ---------------------------------------------------------------------------
// Gate + top-3-past chunk selection (fp32 — selection must stay exact).
// ---------------------------------------------------------------------------
__global__ __launch_bounds__(256) void gate_topk(const float* __restrict__ q,
                                                 const float* __restrict__ kg,
                                                 int* __restrict__ amask) {
  int wid = threadIdx.x >> 6;
  int lane = threadIdx.x & 63;
  int s = blockIdx.x * 4 + wid;
  int h = blockIdx.y;
  int myc = s >> 8;
  float qd = q[((size_t)s * NH + h) * HD + lane];
  float g[NCH];
#pragma unroll
  for (int c = 0; c < NCH; ++c) {
    float p = qd * kg[((size_t)c * NH + h) * HD + lane];
#pragma unroll
    for (int off = 32; off; off >>= 1) p += __shfl_xor(p, off);
    g[c] = p;
  }
  int chosen = 0;
#pragma unroll
  for (int pick = 0; pick < 3; ++pick) {
    float best = -INFINITY;
    int bi = -1;
#pragma unroll
    for (int c = 0; c < NCH; ++c) {
      if (c < myc && !((chosen >> c) & 1) && g[c] > best) {
        best = g[c];
        bi = c;
      }
    }
    if (bi >= 0) chosen |= (1 << bi);
  }
  int mask = chosen | (1 << myc);
  if (lane == 0) amask[h * S_LEN + s] = mask;
}

// ---------------------------------------------------------------------------
// K fp32 [s][h][d] -> fragment-major bf16: khf[h][tile][frag=st*2+half][lane][8]
// ---------------------------------------------------------------------------
__global__ __launch_bounds__(256) void repack_kf(const float* __restrict__ k,
                                                 unsigned short* __restrict__ khf) {
  __shared__ float tl[64][68];
  const int t = blockIdx.x;   // 64-key tile
  const int h = blockIdx.y;
  const int tid = threadIdx.x;
  const int t0 = t * 64;
  {
    const int r = tid >> 2, c4 = (tid & 3) * 16;
    const float* src = &k[((size_t)(t0 + r) * NH + h) * HD + c4];
#pragma unroll
    for (int qd = 0; qd < 4; ++qd)
      *reinterpret_cast<float4*>(&tl[r][c4 + qd * 4]) =
          *reinterpret_cast<const float4*>(src + qd * 4);
  }
  __syncthreads();
  const int w = tid >> 6, l = tid & 63;
  const int l15 = l & 15, g = l >> 4;
  unsigned short* ob = khf + (((size_t)h * 32 + t) * 8) * 512;
#pragma unroll
  for (int ff = 0; ff < 2; ++ff) {
    const int f = 2 * w + ff;
    const int st = f >> 1, half = f & 1;
    const float* rp = &tl[st * 16 + l15][g * 8 + half * 32];
    ushort4 u0 = make_ushort4(f2bf(rp[0]), f2bf(rp[1]), f2bf(rp[2]), f2bf(rp[3]));
    ushort4 u1 = make_ushort4(f2bf(rp[4]), f2bf(rp[5]), f2bf(rp[6]), f2bf(rp[7]));
    *reinterpret_cast<ushort4*>(ob + (size_t)f * 512 + l * 8) = u0;
    *reinterpret_cast<ushort4*>(ob + (size_t)f * 512 + l * 8 + 4) = u1;
  }
}

// ---------------------------------------------------------------------------
// V fp32 [s][h][d] -> fragment-major bf16: vhf[h][tile][fp=st*2+p][lane][8]
// ---------------------------------------------------------------------------
__global__ __launch_bounds__(256) void repack_vf(const float* __restrict__ v,
                                                 unsigned short* __restrict__ vhf) {
  __shared__ float tl[64][68];
  const int t = blockIdx.x;
  const int h = blockIdx.y;
  const int tid = threadIdx.x;
  const int t0 = t * 64;
  {
    const int r = tid >> 2, c4 = (tid & 3) * 16;
    const float* src = &v[((size_t)(t0 + r) * NH + h) * HD + c4];
#pragma unroll
    for (int qd = 0; qd < 4; ++qd)
      *reinterpret_cast<float4*>(&tl[r][c4 + qd * 4]) =
          *reinterpret_cast<const float4*>(src + qd * 4);
  }
  __syncthreads();
  const int w = tid >> 6, l = tid & 63;
  const int l15 = l & 15, g = l >> 4;
  unsigned short* ob = vhf + (((size_t)h * 32 + t) * 8) * 512;
#pragma unroll
  for (int ff = 0; ff < 2; ++ff) {
    const int fp = 2 * w + ff;
    const int st = fp >> 1, p = fp & 1;
    unsigned short u[8];
#pragma unroll
    for (int e = 0; e < 8; ++e) {
      const int cb = 2 * p + (e >> 2);
      const int j = e & 3;
      u[e] = f2bf(tl[st * 16 + 4 * g + j][cb * 16 + l15]);
    }
    *reinterpret_cast<ushort4*>(ob + (size_t)fp * 512 + l * 8) =
        make_ushort4(u[0], u[1], u[2], u[3]);
    *reinterpret_cast<ushort4*>(ob + (size_t)fp * 512 + l * 8 + 4) =
        make_ushort4(u[4], u[5], u[6], u[7]);
  }
}

// ---------------------------------------------------------------------------
// MFMA flash attention, split-K across 4 waves, fragment-major K/V loads.
// ---------------------------------------------------------------------------
__global__ __launch_bounds__(256) void attn_mfma(const float* __restrict__ q,
                                                 const unsigned short* __restrict__ khf,
                                                 const unsigned short* __restrict__ vhf,
                                                 const int* __restrict__ amask,
                                                 float* __restrict__ o) {
  const int B = blockIdx.x;
  const int xcd = B & 7;
  const int jb = B >> 3;
  const int h = xcd + ((jb >> 7) << 3);
  const int s0 = (jb & 127) << 4;
  const int tid = threadIdx.x;
  const int wid = tid >> 6;
  const int lane = tid & 63;
  const int l15 = lane & 15, g = lane >> 4;
  const int myS = s0 + l15;
  const int myc = s0 >> 8;
  const int ktm = (s0 & (CS - 1)) >> 6;

  __shared__ float lm[4][16];
  __shared__ float ll[4][16];
  __shared__ float lacc[4][16][64];

  // Q B-frag, scale 1/8 folded (exact for pow2)
  const float* qrow = q + ((size_t)myS * NH + h) * HD;
  bf16x8 qf[2];
#pragma unroll
  for (int hf = 0; hf < 2; ++hf)
#pragma unroll
    for (int jj = 0; jj < 8; ++jj)
      qf[hf][jj] = (short)f2bf(qrow[hf * 32 + g * 8 + jj] * 0.125f);

  int mymask = amask[h * S_LEN + myS];
  int wmask = mymask;
  wmask |= __shfl_xor(wmask, 1);
  wmask |= __shfl_xor(wmask, 2);
  wmask |= __shfl_xor(wmask, 4);
  wmask |= __shfl_xor(wmask, 8);
  const int pmask = wmask & ~(1 << myc);
  const int ntot = (ktm + 1) + 4 * __popc(pmask);

  // j -> (t0 | lane_on<<16). Self-chunk tiles first, then past chunks.
  auto DEC = [&](int j) -> int {
    if (j <= ktm) return ((s0 & ~255) + (j << 6)) | (1 << 16);
    int jj = j - ktm - 1;
    int mm = pmask;
    int drop = jj >> 2;
    for (int b = 0; b < drop; ++b) mm &= mm - 1;
    int c = __ffs(mm) - 1;
    return ((c << 8) + ((jj & 3) << 6)) | (((mymask >> c) & 1) << 16);
  };

  const unsigned short* khh = khf + (((size_t)h * 32) << 12);
  const unsigned short* vhh = vhf + (((size_t)h * 32) << 12);

  bf16x8 kr[4][2];
  auto LOADK = [&](int t0) {
    const unsigned short* tb = khh + ((size_t)(t0 >> 6) << 12) + lane * 8;
#pragma unroll
    for (int f = 0; f < 8; ++f)
      kr[f >> 1][f & 1] = *reinterpret_cast<const bf16x8*>(tb + f * 512);
  };

  float m = -1e30f, lsum = 0.f;
  f32x4 accv[4];
#pragma unroll
  for (int i = 0; i < 4; ++i) accv[i] = (f32x4){0.f, 0.f, 0.f, 0.f};

  if (wid < ntot) LOADK(DEC(wid) & 0xFFFF);

#pragma unroll
  for (int i = 0; i < 8; ++i) {
    const int j = wid + (i << 2);
    if (j < ntot) {
      const int ent = DEC(j);
      const int t0 = ent & 0xFFFF;
      const bool lane_on = (ent >> 16) != 0;
      const bool diag = (j == ktm);

      // V fragments (wave-contiguous; issued early, consumed after softmax)
      const unsigned short* vtb = vhh + ((size_t)(t0 >> 6) << 12) + lane * 8;
      bf16x4 vb[4][4];
#pragma unroll
      for (int fp = 0; fp < 8; ++fp) {
        bf16x8 wv = *reinterpret_cast<const bf16x8*>(vtb + fp * 512);
        const int st = fp >> 1, pp = fp & 1;
#pragma unroll
        for (int jj = 0; jj < 4; ++jj) {
          vb[st][2 * pp][jj] = wv[jj];
          vb[st][2 * pp + 1][jj] = wv[4 + jj];
        }
      }

      // QK^T (scale pre-folded into qf)
      float p[16];
      __builtin_amdgcn_s_setprio(1);
#pragma unroll
      for (int st = 0; st < 4; ++st) {
        f32x4 d = (f32x4){0.f, 0.f, 0.f, 0.f};
        d = __builtin_amdgcn_mfma_f32_16x16x32_bf16(kr[st][0], qf[0], d, 0, 0, 0);
        d = __builtin_amdgcn_mfma_f32_16x16x32_bf16(kr[st][1], qf[1], d, 0, 0, 0);
#pragma unroll
        for (int r = 0; r < 4; ++r) {
          bool ok = lane_on && (!diag || (t0 + st * 16 + 4 * g + r <= myS));
          p[st * 4 + r] = ok ? d[r] : -1e30f;
        }
      }
      __builtin_amdgcn_s_setprio(0);

      // Prefetch next tile's K into the same regs (WAR-ordered)
      if (j + 4 < ntot) LOADK(DEC(j + 4) & 0xFFFF);

      // Row max (4-lane groups share a row via xor 16/32)
      float mt = -1e30f;
#pragma unroll
      for (int ii = 0; ii < 16; ++ii) mt = fmaxf(mt, p[ii]);
      mt = fmaxf(mt, __shfl_xor(mt, 16));
      mt = fmaxf(mt, __shfl_xor(mt, 32));

      const float mnew = fmaxf(m, mt);
      const float corr = __expf(m - mnew);
      float ps = 0.f;
#pragma unroll
      for (int ii = 0; ii < 16; ++ii) {
        float pv = (p[ii] > -1e29f) ? __expf(p[ii] - mnew) : 0.f;
        p[ii] = pv;
        ps += pv;
      }
      ps += __shfl_xor(ps, 16);
      ps += __shfl_xor(ps, 32);
      lsum = lsum * corr + ps;
      m = mnew;

      // Rescale accumulator (acc rows are q-rows 4g+r; corr lives at lane 4g+r)
#pragma unroll
      for (int r = 0; r < 4; ++r) {
        float cr = __shfl(corr, 4 * g + r);
#pragma unroll
        for (int cb = 0; cb < 4; ++cb) accv[cb][r] *= cr;
      }

      // PV: P fragment (A of 16x16x16) is exactly the S^T output fragment
      __builtin_amdgcn_s_setprio(1);
#pragma unroll
      for (int st = 0; st < 4; ++st) {
        bf16x4 pa;
#pragma unroll
        for (int jj = 0; jj < 4; ++jj) pa[jj] = (short)f2bf(p[st * 4 + jj]);
#pragma unroll
        for (int cb = 0; cb < 4; ++cb)
          accv[cb] = mfma16(pa, vb[st][cb], accv[cb]);
      }
      __builtin_amdgcn_s_setprio(0);
    }
  }

  // ---- store partials to LDS ----
#pragma unroll
  for (int cb = 0; cb < 4; ++cb)
#pragma unroll
    for (int r = 0; r < 4; ++r) lacc[wid][cb * 4 + r][lane] = accv[cb][r];
  if (lane < 16) {
    lm[wid][lane] = m;
    ll[wid][lane] = lsum;
  }
  __syncthreads();

  // ---- merge: wave `wid` produces dim-block cb = wid ----
  float outv[4];
#pragma unroll
  for (int r = 0; r < 4; ++r) {
    const int row = 4 * g + r;
    float m0 = lm[0][row], m1 = lm[1][row], m2 = lm[2][row], m3 = lm[3][row];
    float mt = fmaxf(fmaxf(m0, m1), fmaxf(m2, m3));
    float e0 = __expf(m0 - mt), e1 = __expf(m1 - mt);
    float e2 = __expf(m2 - mt), e3 = __expf(m3 - mt);
    float ltot = ll[0][row] * e0 + ll[1][row] * e1 + ll[2][row] * e2 + ll[3][row] * e3;
    float a = lacc[0][wid * 4 + r][lane] * e0 + lacc[1][wid * 4 + r][lane] * e1 +
              lacc[2][wid * 4 + r][lane] * e2 + lacc[3][wid * 4 + r][lane] * e3;
    outv[r] = a / ltot;
  }
#pragma unroll
  for (int r = 0; r < 4; ++r)
    o[((size_t)(s0 + 4 * g + r) * NH + h) * HD + wid * 16 + l15] = outv[r];
}

// ---------------------------------------------------------------------------
// RMS-norm + sigmoid gate; emits bf16 for the out-proj A-operand.
// ---------------------------------------------------------------------------
__global__ __launch_bounds__(256) void postproc(const float* __restrict__ o,
                                                const float* __restrict__ g,
                                                const float* __restrict__ w,
                                                unsigned short* __restrict__ o2h) {
  int idx = blockIdx.x * 256 + threadIdx.x;
  int lane = threadIdx.x & 63;
  float val = o[idx];
  float ss = val * val;
#pragma unroll
  for (int off = 32; off; off >>= 1) ss += __shfl_xor(ss, off);
  float r = rsqrtf(ss * (1.0f / HD) + 1e-6f);
  float gv = g[idx];
  float sig = 1.0f / (1.0f + expf(-gv));
  o2h[idx] = f2bf(val * r * w[lane] * sig);
}

// ---------------------------------------------------------------------------
extern "C" void kernel_launch(void* const* d_in, const int* in_sizes, int n_in,
                              void* d_out, int out_size, void* d_ws, size_t ws_size,
                              hipStream_t stream) {
  const float* x   = (const float*)d_in[0];
  const float* Wq  = (const float*)d_in[1];
  const float* Wk  = (const float*)d_in[2];
  const float* Wv  = (const float*)d_in[3];
  const float* Wo  = (const float*)d_in[4];
  const float* Wg1 = (const float*)d_in[5];
  const float* Wg2 = (const float*)d_in[6];
  const float* onw = (const float*)d_in[7];
  float* out = (float*)d_out;

  const size_t BIG = (size_t)S_LEN * D_DIM;  // 4M elements
  float* q    = (float*)d_ws;
  float* k    = q + BIG;
  float* v    = k + BIG;
  float* o    = v + BIG;
  float* gbuf = o + BIG;
  float* kg   = gbuf + BIG;                    // NCH*NH*HD
  int* amask  = (int*)(kg + NCH * NH * HD);    // NH*S
  unsigned short* xh  = (unsigned short*)(amask + NH * S_LEN);
  unsigned short* xl  = xh + BIG;
  unsigned short* whq = xl + BIG;
  unsigned short* wlq = whq + BIG;
  unsigned short* whk = wlq + BIG;
  unsigned short* wlk = whk + BIG;
  unsigned short* whv = wlk + BIG;
  unsigned short* whg = whv + BIG;
  unsigned short* khf = whg + BIG;
  unsigned short* vhf = khf + BIG;
  unsigned short* o2h = vhf + BIG;

  const dim3 gT(32, 32);
  // Split x into hi/lo bf16
  repack_x_hl<<<(int)(BIG / 4 / 256), 256, 0, stream>>>(x, xh, xl);
  // Fused weight repacks: Wq(lo), Wk(lo), Wv(hi)
  {
    RT3 rt;
    rt.W[0] = Wq;  rt.hiT[0] = whq; rt.loT[0] = wlq; rt.has_lo[0] = 1;
    rt.W[1] = Wk;  rt.hiT[1] = whk; rt.loT[1] = wlk; rt.has_lo[1] = 1;
    rt.W[2] = Wv;  rt.hiT[2] = whv; rt.loT[2] = whv; rt.has_lo[2] = 0;
    repack_T3<<<dim3(32, 32, 3), 256, 0, stream>>>(rt);
  }
  // W' = Wg1 @ Wg2 (fp32, K=64) into o; repack to whg
  sgemm_f32<<<dim3(16, 16), 256, 0, stream>>>(Wg1, Wg2, o, D_DIM, D_DIM, HD);
  repack_T<<<gT, 256, 0, stream>>>(o, whg, nullptr, D_DIM, D_DIM, 0);

  // Fused Q(3) K(3) V(1) G(1) projections — 128x128 tile, 1024 blocks,
  // XCD-balanced (each XCD: one 3-pass group + one 1-pass group)
  {
    QKVG gg;
    gg.xh = xh; gg.xl = xl;
    gg.wh[0] = whq; gg.wh[1] = whk; gg.wh[2] = whv; gg.wh[3] = whg;
    gg.wl[0] = wlq; gg.wl[1] = wlk; gg.wl[2] = nullptr; gg.wl[3] = nullptr;
    gg.C[0] = q; gg.C[1] = k; gg.C[2] = v; gg.C[3] = gbuf;
    gg.np[0] = 3; gg.np[1] = 3; gg.np[2] = 1; gg.np[3] = 1;
    gemm_qkvg<<<1024, 256, 0, stream>>>(gg);
  }

  // RoPE
  rope_qk<<<S_LEN * NH * (HD / 2) / 256, 256, 0, stream>>>(q, k);
  // Chunk means + gating (fp32)
  chunk_mean<<<(NCH * NH * HD + 255) / 256, 256, 0, stream>>>(k, kg);
  gate_topk<<<dim3(S_LEN / 4, NH), 256, 0, stream>>>(q, kg, amask);
  // Fragment-major repacks for attention
  repack_kf<<<dim3(S_LEN / 64, NH), 256, 0, stream>>>(k, khf);
  repack_vf<<<dim3(S_LEN / 64, NH), 256, 0, stream>>>(v, vhf);
  // Attention (overwrites o): 4-wave split-K, head-locality XCD swizzle
  attn_mfma<<<(S_LEN / 16) * NH, 256, 0, stream>>>(q, khf, vhf, amask, o);
  // RMS-norm + sigmoid gate -> bf16
  postproc<<<(int)(BIG / 256), 256, 0, stream>>>(o, gbuf, onw, o2h);
  // out = o2 @ Wo (1-pass bf16); reuse whq for Wo^T
  repack_T<<<gT, 256, 0, stream>>>(Wo, whq, nullptr, D_DIM, D_DIM, 0);
  {
    G3 g3{{o2h, o2h, o2h}, {whq, whq, whq}, 1};
    gemm_bt<<<(S_LEN / 64) * (D_DIM / 128), 256, 0, stream>>>(g3, out, S_LEN, D_DIM, D_DIM);
  }
}

// Round 13
// 343.321 us; speedup vs baseline: 1.9548x; 1.0791x over previous
//
#include <hip/hip_runtime.h>
#include <hip/hip_bf16.h>
#include <math.h>

#define S_LEN 2048
#define D_DIM 2048
#define NH 32
#define HD 64
#define CS 256
#define NCH 8

typedef __attribute__((ext_vector_type(8))) short bf16x8;
typedef __attribute__((ext_vector_type(4))) short bf16x4;
typedef __attribute__((ext_vector_type(4))) float f32x4;

__device__ __forceinline__ unsigned short f2bf(float f) {
  unsigned int u = __builtin_bit_cast(unsigned int, f);
  unsigned int r = (u + 0x7fffu + ((u >> 16) & 1u)) >> 16;
  return (unsigned short)r;
}
__device__ __forceinline__ float bf2f(unsigned short b) {
  unsigned int u = ((unsigned int)b) << 16;
  return __builtin_bit_cast(float, u);
}

__device__ __forceinline__ f32x4 mfma16(bf16x4 a, bf16x4 b, f32x4 c) {
#if __has_builtin(__builtin_amdgcn_mfma_f32_16x16x16_bf16)
  return __builtin_amdgcn_mfma_f32_16x16x16_bf16(a, b, c, 0, 0, 0);
#elif __has_builtin(__builtin_amdgcn_mfma_f32_16x16x16bf16_1k)
  return __builtin_amdgcn_mfma_f32_16x16x16bf16_1k(a, b, c, 0, 0, 0);
#else
  asm("v_mfma_f32_16x16x16_bf16 %0, %1, %2, %0" : "+v"(c) : "v"(a), "v"(b));
  return c;
#endif
}

__device__ __forceinline__ void gload16(const void* gp, void* lp) {
  __builtin_amdgcn_global_load_lds(
      (const __attribute__((address_space(1))) unsigned int*)gp,
      (__attribute__((address_space(3))) unsigned int*)lp, 16, 0, 0);
}

// ---------------------------------------------------------------------------
// RoPE cos/sin table: rope_tab[s][d] = (cosf(s*inv(d)), sinf(s*inv(d))),
// d in [0,32). Same float expressions as the reference rope.
// ---------------------------------------------------------------------------
__global__ __launch_bounds__(256) void rope_tab_k(float2* __restrict__ tab) {
  int idx = blockIdx.x * 256 + threadIdx.x;  // over S_LEN*32
  if (idx >= S_LEN * 32) return;
  int d = idx & 31;
  int s = idx >> 5;
  float inv = 1.0f / powf(10000.0f, (float)d * (1.0f / 32.0f));
  float fr = (float)s * inv;
  tab[idx] = make_float2(cosf(fr), sinf(fr));
}

// ---------------------------------------------------------------------------
// Fused QKVG GEMM, 128x128 tile (4 waves x 64x64), BK=64, 32KB LDS.
// Balanced XCD decode (even XCDs {Q,V}, odd {K,G}; col-groups of 4 panels).
// RoPE fused into the epilogue for Q,K outputs (pairs (n, n+2) = (d, d+32)).
// ---------------------------------------------------------------------------
struct QKVG {
  const unsigned short* xh;
  const unsigned short* xl;
  const unsigned short* wh[4];
  const unsigned short* wl[4];
  float* C[4];
  int np[4];
  const float2* rtab;
};

__global__ __launch_bounds__(256) void gemm_qkvg(QKVG g) {
  __shared__ __align__(16) unsigned short Als[128 * 64];
  __shared__ __align__(16) unsigned short Bls[128 * 64];
  const int tid = threadIdx.x;
  const int wid = tid >> 6, lane = tid & 63;
  const int l15 = lane & 15, l4 = lane >> 4;
  const int wr = wid >> 1, wc = wid & 1;
  const int K = D_DIM, N = D_DIM;

  const int bid = blockIdx.x;
  const int xcd = bid & 7;
  const int local = bid >> 3;
  const int c = local >> 6;
  const int idx = local & 63;
  const int out = (xcd & 1) + 2 * c;
  const int grp = xcd >> 1;
  const int row0 = (idx >> 2) << 7;
  const int col0 = ((grp << 2) + (idx & 3)) << 7;

  f32x4 acc[4][4];
#pragma unroll
  for (int m = 0; m < 4; ++m)
#pragma unroll
    for (int n = 0; n < 4; ++n) acc[m][n] = (f32x4){0.f, 0.f, 0.f, 0.f};

  const int np = g.np[out];
  for (int p = 0; p < np; ++p) {
    const unsigned short* Ap = (p == 2) ? g.xl : g.xh;
    const unsigned short* Bp = (p == 1) ? g.wl[out] : g.wh[out];
    for (int kt = 0; kt < K; kt += 64) {
      __syncthreads();
#pragma unroll
      for (int i = 0; i < 4; ++i) {
        const int Lb = i * 4096 + wid * 1024;
        const int L = Lb + lane * 16;
        const int row = L >> 7;
        const int s = (L >> 4) & 7;
        const int cofs = (s ^ (row & 7)) << 3;
        gload16(Ap + (size_t)(row0 + row) * K + kt + cofs, (char*)Als + Lb);
        gload16(Bp + (size_t)(col0 + row) * K + kt + cofs, (char*)Bls + Lb);
      }
      asm volatile("s_waitcnt vmcnt(0)" ::: "memory");
      __syncthreads();
#pragma unroll
      for (int ks = 0; ks < 2; ++ks) {
        bf16x8 af[4], bfr[4];
#pragma unroll
        for (int m = 0; m < 4; ++m) {
          int row = wr * 64 + m * 16 + l15;
          int s = (ks * 4 + l4) ^ (row & 7);
          af[m] = *reinterpret_cast<const bf16x8*>(&Als[row * 64 + s * 8]);
        }
#pragma unroll
        for (int n = 0; n < 4; ++n) {
          int col = wc * 64 + n * 16 + l15;
          int s = (ks * 4 + l4) ^ (col & 7);
          bfr[n] = *reinterpret_cast<const bf16x8*>(&Bls[col * 64 + s * 8]);
        }
#pragma unroll
        for (int m = 0; m < 4; ++m)
#pragma unroll
          for (int n = 0; n < 4; ++n)
            acc[m][n] = __builtin_amdgcn_mfma_f32_16x16x32_bf16(af[m], bfr[n], acc[m][n], 0, 0, 0);
      }
    }
  }

  // Fused RoPE for Q,K: pair (n, n+2) = head-dims (d, d+32), d = n*16+l15.
  if (out < 2) {
#pragma unroll
    for (int n = 0; n < 2; ++n) {
      const int d = n * 16 + l15;
#pragma unroll
      for (int m = 0; m < 4; ++m)
#pragma unroll
        for (int r = 0; r < 4; ++r) {
          const int s = row0 + wr * 64 + m * 16 + l4 * 4 + r;
          float2 cs = g.rtab[s * 32 + d];
          float a1 = acc[m][n][r], a2 = acc[m][n + 2][r];
          acc[m][n][r] = a1 * cs.x - a2 * cs.y;
          acc[m][n + 2][r] = a2 * cs.x + a1 * cs.y;
        }
    }
  }

  float* C = g.C[out];
#pragma unroll
  for (int m = 0; m < 4; ++m)
#pragma unroll
    for (int n = 0; n < 4; ++n)
#pragma unroll
      for (int r = 0; r < 4; ++r)
        C[(size_t)(row0 + wr * 64 + m * 16 + l4 * 4 + r) * N + col0 + wc * 64 + n * 16 + l15] =
            acc[m][n][r];
}

// ---------------------------------------------------------------------------
// bf16 MFMA GEMM 64x128 (out-projection).
// ---------------------------------------------------------------------------
struct G3 {
  const unsigned short* A[3];
  const unsigned short* B[3];
  int np;
};

__global__ __launch_bounds__(256) void gemm_bt(G3 g, float* __restrict__ C,
                                               int M, int N, int K) {
  __shared__ __align__(16) unsigned short Als[64 * 64];
  __shared__ __align__(16) unsigned short Bls[128 * 64];
  const int tid = threadIdx.x;
  const int wid = tid >> 6, lane = tid & 63;
  const int l15 = lane & 15, l4 = lane >> 4;
  const int wr = wid >> 1, wc = wid & 1;
  const int nbx = N >> 7;
  int bid = blockIdx.x;
  const int nwg = gridDim.x;
  if ((nwg & 7) == 0) {
    int q = nwg >> 3;
    bid = (bid & 7) * q + (bid >> 3);
  }
  const int row0 = (bid / nbx) << 6;
  const int col0 = (bid % nbx) << 7;

  f32x4 acc[2][4];
#pragma unroll
  for (int m = 0; m < 2; ++m)
#pragma unroll
    for (int n = 0; n < 4; ++n) acc[m][n] = (f32x4){0.f, 0.f, 0.f, 0.f};

  for (int p = 0; p < g.np; ++p) {
    const unsigned short* Ap = g.A[p];
    const unsigned short* Bp = g.B[p];
    for (int kt = 0; kt < K; kt += 64) {
      __syncthreads();
#pragma unroll
      for (int i = 0; i < 2; ++i) {
        const int Lb = i * 4096 + wid * 1024;
        const int L = Lb + lane * 16;
        const int row = L >> 7;
        const int s = (L >> 4) & 7;
        const int cofs = (s ^ (row & 7)) << 3;
        gload16(Ap + (size_t)(row0 + row) * K + kt + cofs, (char*)Als + Lb);
      }
#pragma unroll
      for (int i = 0; i < 4; ++i) {
        const int Lb = i * 4096 + wid * 1024;
        const int L = Lb + lane * 16;
        const int row = L >> 7;
        const int s = (L >> 4) & 7;
        const int cofs = (s ^ (row & 7)) << 3;
        gload16(Bp + (size_t)(col0 + row) * K + kt + cofs, (char*)Bls + Lb);
      }
      asm volatile("s_waitcnt vmcnt(0)" ::: "memory");
      __syncthreads();
#pragma unroll
      for (int ks = 0; ks < 2; ++ks) {
        bf16x8 af[2], bfr[4];
#pragma unroll
        for (int m = 0; m < 2; ++m) {
          int row = wr * 32 + m * 16 + l15;
          int s = (ks * 4 + l4) ^ (row & 7);
          af[m] = *reinterpret_cast<const bf16x8*>(&Als[row * 64 + s * 8]);
        }
#pragma unroll
        for (int n = 0; n < 4; ++n) {
          int col = wc * 64 + n * 16 + l15;
          int s = (ks * 4 + l4) ^ (col & 7);
          bfr[n] = *reinterpret_cast<const bf16x8*>(&Bls[col * 64 + s * 8]);
        }
#pragma unroll
        for (int m = 0; m < 2; ++m)
#pragma unroll
          for (int n = 0; n < 4; ++n)
            acc[m][n] = __builtin_amdgcn_mfma_f32_16x16x32_bf16(af[m], bfr[n], acc[m][n], 0, 0, 0);
      }
    }
  }

#pragma unroll
  for (int m = 0; m < 2; ++m)
#pragma unroll
    for (int n = 0; n < 4; ++n)
#pragma unroll
      for (int r = 0; r < 4; ++r)
        C[(size_t)(row0 + wr * 32 + m * 16 + l4 * 4 + r) * N + col0 + wc * 64 + n * 16 + l15] =
            acc[m][n][r];
}

// ---------------------------------------------------------------------------
// fp32 SGEMM for W' = Wg1 @ Wg2 (K=64), writing W'^T bf16 directly.
// ---------------------------------------------------------------------------
__global__ __launch_bounds__(256) void sgemm_f32T(const float* __restrict__ A,
                                                  const float* __restrict__ B,
                                                  unsigned short* __restrict__ CT,
                                                  int M, int N, int K) {
  __shared__ float As[8][128];
  __shared__ float Bs[8][128];
  const int tid = threadIdx.x;
  const int row0 = blockIdx.y * 128;
  const int col0 = blockIdx.x * 128;
  const int tm = (tid / 16) * 8;
  const int tn = (tid % 16) * 8;
  const int arow = tid >> 1;
  const int acol = (tid & 1) * 4;
  const int brow = tid >> 5;
  const int bcol = (tid & 31) * 4;

  float acc[8][8];
#pragma unroll
  for (int i = 0; i < 8; ++i)
#pragma unroll
    for (int j = 0; j < 8; ++j) acc[i][j] = 0.f;

  for (int k0 = 0; k0 < K; k0 += 8) {
    float4 av = make_float4(0.f, 0.f, 0.f, 0.f);
    if (row0 + arow < M) {
      int kb = k0 + acol;
      av = *reinterpret_cast<const float4*>(&A[(size_t)(row0 + arow) * K + kb]);
    }
    As[acol + 0][arow] = av.x;
    As[acol + 1][arow] = av.y;
    As[acol + 2][arow] = av.z;
    As[acol + 3][arow] = av.w;
    float4 bv = make_float4(0.f, 0.f, 0.f, 0.f);
    if (k0 + brow < K) {
      bv = *reinterpret_cast<const float4*>(&B[(size_t)(k0 + brow) * N + col0 + bcol]);
    }
    *reinterpret_cast<float4*>(&Bs[brow][bcol]) = bv;
    __syncthreads();
#pragma unroll
    for (int kk = 0; kk < 8; ++kk) {
      float a[8], b[8];
      *reinterpret_cast<float4*>(&a[0]) = *reinterpret_cast<const float4*>(&As[kk][tm]);
      *reinterpret_cast<float4*>(&a[4]) = *reinterpret_cast<const float4*>(&As[kk][tm + 4]);
      *reinterpret_cast<float4*>(&b[0]) = *reinterpret_cast<const float4*>(&Bs[kk][tn]);
      *reinterpret_cast<float4*>(&b[4]) = *reinterpret_cast<const float4*>(&Bs[kk][tn + 4]);
#pragma unroll
      for (int i = 0; i < 8; ++i)
#pragma unroll
        for (int j = 0; j < 8; ++j) acc[i][j] = fmaf(a[i], b[j], acc[i][j]);
    }
    __syncthreads();
  }
  // Write transposed bf16: CT[n][k], 8 contiguous k per (n) -> 2x ushort4
#pragma unroll
  for (int j = 0; j < 8; ++j) {
    const int n = col0 + tn + j;
    ushort4 u0 = make_ushort4(f2bf(acc[0][j]), f2bf(acc[1][j]), f2bf(acc[2][j]), f2bf(acc[3][j]));
    ushort4 u1 = make_ushort4(f2bf(acc[4][j]), f2bf(acc[5][j]), f2bf(acc[6][j]), f2bf(acc[7][j]));
    *reinterpret_cast<ushort4*>(&CT[(size_t)n * M + row0 + tm]) = u0;
    *reinterpret_cast<ushort4*>(&CT[(size_t)n * M + row0 + tm + 4]) = u1;
  }
}

// ---------------------------------------------------------------------------
// x fp32 -> xh, xl bf16 (hi/lo split).
// ---------------------------------------------------------------------------
__global__ __launch_bounds__(256) void repack_x_hl(const float* __restrict__ x,
                                                   unsigned short* __restrict__ xh,
                                                   unsigned short* __restrict__ xl) {
  int i = (blockIdx.x * 256 + threadIdx.x) * 4;
  float4 v = *reinterpret_cast<const float4*>(&x[i]);
  float f[4] = {v.x, v.y, v.z, v.w};
  unsigned short h[4], l[4];
#pragma unroll
  for (int j = 0; j < 4; ++j) {
    h[j] = f2bf(f[j]);
    l[j] = f2bf(f[j] - bf2f(h[j]));
  }
  *reinterpret_cast<ushort4*>(&xh[i]) = make_ushort4(h[0], h[1], h[2], h[3]);
  *reinterpret_cast<ushort4*>(&xl[i]) = make_ushort4(l[0], l[1], l[2], l[3]);
}

// ---------------------------------------------------------------------------
// Fused 4-weight transpose repack (Wq, Wk with lo; Wv, Wo hi-only).
// ---------------------------------------------------------------------------
struct RT4 {
  const float* W[4];
  unsigned short* hiT[4];
  unsigned short* loT[4];
  int has_lo[4];
};

__global__ __launch_bounds__(256) void repack_T4(RT4 a) {
  __shared__ float t[64][65];
  const int wsel = blockIdx.z;
  const float* W = a.W[wsel];
  unsigned short* hiT = a.hiT[wsel];
  unsigned short* loT = a.loT[wsel];
  const int has_lo = a.has_lo[wsel];
  const int k0 = blockIdx.y * 64, n0 = blockIdx.x * 64;
  const int tid = threadIdx.x;
  const int c = tid & 63, rr = tid >> 6;
#pragma unroll
  for (int r = 0; r < 16; ++r) {
    int kr = r * 4 + rr;
    t[kr][c] = W[(size_t)(k0 + kr) * D_DIM + n0 + c];
  }
  __syncthreads();
#pragma unroll
  for (int r = 0; r < 16; ++r) {
    int n = r * 4 + rr;
    float f = t[c][n];
    unsigned short hb = f2bf(f);
    hiT[(size_t)(n0 + n) * D_DIM + k0 + c] = hb;
    if (has_lo) loT[(size_t)(n0 + n) * D_DIM + k0 + c] = f2bf(f - bf2f(hb));
  }
}

// ---------------------------------------------------------------------------
// Chunk means of k.
// ---------------------------------------------------------------------------
__global__ __launch_bounds__(256) void chunk_mean(const float* __restrict__ k,
                                                  float* __restrict__ kg) {
  int idx = blockIdx.x * 256 + threadIdx.x;
  if (idx >= NCH * NH * HD) return;
  int c = idx / (NH * HD);
  int hd = idx % (NH * HD);
  float sum = 0.f;
  for (int t = 0; t < CS; ++t) sum += k[(size_t)(c * CS + t) * (NH * HD) + hd];
  kg[idx] = sum * (1.0f / CS);
}

// ---------------------------------------------------------------------------
// Gate + top-3-past chunk selection (fp32).
// ---------------------------------------------------------------------------
__global__ __launch_bounds__(256) void gate_topk(const float* __restrict__ q,
                                                 const float* __restrict__ kg,
                                                 int* __restrict__ amask) {
  int wid = threadIdx.x >> 6;
  int lane = threadIdx.x & 63;
  int s = blockIdx.x * 4 + wid;
  int h = blockIdx.y;
  int myc = s >> 8;
  float qd = q[((size_t)s * NH + h) * HD + lane];
  float g[NCH];
#pragma unroll
  for (int c = 0; c < NCH; ++c) {
    float p = qd * kg[((size_t)c * NH + h) * HD + lane];
#pragma unroll
    for (int off = 32; off; off >>= 1) p += __shfl_xor(p, off);
    g[c] = p;
  }
  int chosen = 0;
#pragma unroll
  for (int pick = 0; pick < 3; ++pick) {
    float best = -INFINITY;
    int bi = -1;
#pragma unroll
    for (int c = 0; c < NCH; ++c) {
      if (c < myc && !((chosen >> c) & 1) && g[c] > best) {
        best = g[c];
        bi = c;
      }
    }
    if (bi >= 0) chosen |= (1 << bi);
  }
  int mask = chosen | (1 << myc);
  if (lane == 0) amask[h * S_LEN + s] = mask;
}

// ---------------------------------------------------------------------------
// K,V fp32 [s][h][d] -> fragment-major bf16 (one kernel, both outputs).
// khf[h][tile][frag=st*2+half][lane][8]; vhf[h][tile][fp=st*2+p][lane][8].
// ---------------------------------------------------------------------------
__global__ __launch_bounds__(256) void repack_kvf(const float* __restrict__ k,
                                                  const float* __restrict__ v,
                                                  unsigned short* __restrict__ khf,
                                                  unsigned short* __restrict__ vhf) {
  __shared__ float tk[64][68];
  __shared__ float tv[64][68];
  const int t = blockIdx.x;
  const int h = blockIdx.y;
  const int tid = threadIdx.x;
  const int t0 = t * 64;
  {
    const int r = tid >> 2, c4 = (tid & 3) * 16;
    const float* sk = &k[((size_t)(t0 + r) * NH + h) * HD + c4];
    const float* sv = &v[((size_t)(t0 + r) * NH + h) * HD + c4];
#pragma unroll
    for (int qd = 0; qd < 4; ++qd) {
      *reinterpret_cast<float4*>(&tk[r][c4 + qd * 4]) =
          *reinterpret_cast<const float4*>(sk + qd * 4);
      *reinterpret_cast<float4*>(&tv[r][c4 + qd * 4]) =
          *reinterpret_cast<const float4*>(sv + qd * 4);
    }
  }
  __syncthreads();
  const int w = tid >> 6, l = tid & 63;
  const int l15 = l & 15, g = l >> 4;
  unsigned short* obk = khf + (((size_t)h * 32 + t) * 8) * 512;
  unsigned short* obv = vhf + (((size_t)h * 32 + t) * 8) * 512;
#pragma unroll
  for (int ff = 0; ff < 2; ++ff) {
    const int f = 2 * w + ff;
    {
      const int st = f >> 1, half = f & 1;
      const float* rp = &tk[st * 16 + l15][g * 8 + half * 32];
      ushort4 u0 = make_ushort4(f2bf(rp[0]), f2bf(rp[1]), f2bf(rp[2]), f2bf(rp[3]));
      ushort4 u1 = make_ushort4(f2bf(rp[4]), f2bf(rp[5]), f2bf(rp[6]), f2bf(rp[7]));
      *reinterpret_cast<ushort4*>(obk + (size_t)f * 512 + l * 8) = u0;
      *reinterpret_cast<ushort4*>(obk + (size_t)f * 512 + l * 8 + 4) = u1;
    }
    {
      const int st = f >> 1, p = f & 1;
      unsigned short u[8];
#pragma unroll
      for (int e = 0; e < 8; ++e) {
        const int cb = 2 * p + (e >> 2);
        const int j = e & 3;
        u[e] = f2bf(tv[st * 16 + 4 * g + j][cb * 16 + l15]);
      }
      *reinterpret_cast<ushort4*>(obv + (size_t)f * 512 + l * 8) =
          make_ushort4(u[0], u[1], u[2], u[3]);
      *reinterpret_cast<ushort4*>(obv + (size_t)f * 512 + l * 8 + 4) =
          make_ushort4(u[4], u[5], u[6], u[7]);
    }
  }
}

// ---------------------------------------------------------------------------
// MFMA flash attention, split-K across 4 waves, fragment-major K/V loads.
// ---------------------------------------------------------------------------
__global__ __launch_bounds__(256) void attn_mfma(const float* __restrict__ q,
                                                 const unsigned short* __restrict__ khf,
                                                 const unsigned short* __restrict__ vhf,
                                                 const int* __restrict__ amask,
                                                 float* __restrict__ o) {
  const int B = blockIdx.x;
  const int xcd = B & 7;
  const int jb = B >> 3;
  const int h = xcd + ((jb >> 7) << 3);
  const int s0 = (jb & 127) << 4;
  const int tid = threadIdx.x;
  const int wid = tid >> 6;
  const int lane = tid & 63;
  const int l15 = lane & 15, g = lane >> 4;
  const int myS = s0 + l15;
  const int myc = s0 >> 8;
  const int ktm = (s0 & (CS - 1)) >> 6;

  __shared__ float lm[4][16];
  __shared__ float ll[4][16];
  __shared__ float lacc[4][16][64];

  const float* qrow = q + ((size_t)myS * NH + h) * HD;
  bf16x8 qf[2];
#pragma unroll
  for (int hf = 0; hf < 2; ++hf)
#pragma unroll
    for (int jj = 0; jj < 8; ++jj)
      qf[hf][jj] = (short)f2bf(qrow[hf * 32 + g * 8 + jj] * 0.125f);

  int mymask = amask[h * S_LEN + myS];
  int wmask = mymask;
  wmask |= __shfl_xor(wmask, 1);
  wmask |= __shfl_xor(wmask, 2);
  wmask |= __shfl_xor(wmask, 4);
  wmask |= __shfl_xor(wmask, 8);
  const int pmask = wmask & ~(1 << myc);
  const int ntot = (ktm + 1) + 4 * __popc(pmask);

  auto DEC = [&](int j) -> int {
    if (j <= ktm) return ((s0 & ~255) + (j << 6)) | (1 << 16);
    int jj = j - ktm - 1;
    int mm = pmask;
    int drop = jj >> 2;
    for (int b = 0; b < drop; ++b) mm &= mm - 1;
    int c = __ffs(mm) - 1;
    return ((c << 8) + ((jj & 3) << 6)) | (((mymask >> c) & 1) << 16);
  };

  const unsigned short* khh = khf + (((size_t)h * 32) << 12);
  const unsigned short* vhh = vhf + (((size_t)h * 32) << 12);

  bf16x8 kr[4][2];
  auto LOADK = [&](int t0) {
    const unsigned short* tb = khh + ((size_t)(t0 >> 6) << 12) + lane * 8;
#pragma unroll
    for (int f = 0; f < 8; ++f)
      kr[f >> 1][f & 1] = *reinterpret_cast<const bf16x8*>(tb + f * 512);
  };

  float m = -1e30f, lsum = 0.f;
  f32x4 accv[4];
#pragma unroll
  for (int i = 0; i < 4; ++i) accv[i] = (f32x4){0.f, 0.f, 0.f, 0.f};

  if (wid < ntot) LOADK(DEC(wid) & 0xFFFF);

#pragma unroll
  for (int i = 0; i < 8; ++i) {
    const int j = wid + (i << 2);
    if (j < ntot) {
      const int ent = DEC(j);
      const int t0 = ent & 0xFFFF;
      const bool lane_on = (ent >> 16) != 0;
      const bool diag = (j == ktm);

      const unsigned short* vtb = vhh + ((size_t)(t0 >> 6) << 12) + lane * 8;
      bf16x4 vb[4][4];
#pragma unroll
      for (int fp = 0; fp < 8; ++fp) {
        bf16x8 wv = *reinterpret_cast<const bf16x8*>(vtb + fp * 512);
        const int st = fp >> 1, pp = fp & 1;
#pragma unroll
        for (int jj = 0; jj < 4; ++jj) {
          vb[st][2 * pp][jj] = wv[jj];
          vb[st][2 * pp + 1][jj] = wv[4 + jj];
        }
      }

      float p[16];
      __builtin_amdgcn_s_setprio(1);
#pragma unroll
      for (int st = 0; st < 4; ++st) {
        f32x4 d = (f32x4){0.f, 0.f, 0.f, 0.f};
        d = __builtin_amdgcn_mfma_f32_16x16x32_bf16(kr[st][0], qf[0], d, 0, 0, 0);
        d = __builtin_amdgcn_mfma_f32_16x16x32_bf16(kr[st][1], qf[1], d, 0, 0, 0);
#pragma unroll
        for (int r = 0; r < 4; ++r) {
          bool ok = lane_on && (!diag || (t0 + st * 16 + 4 * g + r <= myS));
          p[st * 4 + r] = ok ? d[r] : -1e30f;
        }
      }
      __builtin_amdgcn_s_setprio(0);

      if (j + 4 < ntot) LOADK(DEC(j + 4) & 0xFFFF);

      float mt = -1e30f;
#pragma unroll
      for (int ii = 0; ii < 16; ++ii) mt = fmaxf(mt, p[ii]);
      mt = fmaxf(mt, __shfl_xor(mt, 16));
      mt = fmaxf(mt, __shfl_xor(mt, 32));

      const float mnew = fmaxf(m, mt);
      const float corr = __expf(m - mnew);
      float ps = 0.f;
#pragma unroll
      for (int ii = 0; ii < 16; ++ii) {
        float pv = (p[ii] > -1e29f) ? __expf(p[ii] - mnew) : 0.f;
        p[ii] = pv;
        ps += pv;
      }
      ps += __shfl_xor(ps, 16);
      ps += __shfl_xor(ps, 32);
      lsum = lsum * corr + ps;
      m = mnew;

#pragma unroll
      for (int r = 0; r < 4; ++r) {
        float cr = __shfl(corr, 4 * g + r);
#pragma unroll
        for (int cb = 0; cb < 4; ++cb) accv[cb][r] *= cr;
      }

      __builtin_amdgcn_s_setprio(1);
#pragma unroll
      for (int st = 0; st < 4; ++st) {
        bf16x4 pa;
#pragma unroll
        for (int jj = 0; jj < 4; ++jj) pa[jj] = (short)f2bf(p[st * 4 + jj]);
#pragma unroll
        for (int cb = 0; cb < 4; ++cb)
          accv[cb] = mfma16(pa, vb[st][cb], accv[cb]);
      }
      __builtin_amdgcn_s_setprio(0);
    }
  }

#pragma unroll
  for (int cb = 0; cb < 4; ++cb)
#pragma unroll
    for (int r = 0; r < 4; ++r) lacc[wid][cb * 4 + r][lane] = accv[cb][r];
  if (lane < 16) {
    lm[wid][lane] = m;
    ll[wid][lane] = lsum;
  }
  __syncthreads();

  float outv[4];
#pragma unroll
  for (int r = 0; r < 4; ++r) {
    const int row = 4 * g + r;
    float m0 = lm[0][row], m1 = lm[1][row], m2 = lm[2][row], m3 = lm[3][row];
    float mt = fmaxf(fmaxf(m0, m1), fmaxf(m2, m3));
    float e0 = __expf(m0 - mt), e1 = __expf(m1 - mt);
    float e2 = __expf(m2 - mt), e3 = __expf(m3 - mt);
    float ltot = ll[0][row] * e0 + ll[1][row] * e1 + ll[2][row] * e2 + ll[3][row] * e3;
    float a = lacc[0][wid * 4 + r][lane] * e0 + lacc[1][wid * 4 + r][lane] * e1 +
              lacc[2][wid * 4 + r][lane] * e2 + lacc[3][wid * 4 + r][lane] * e3;
    outv[r] = a / ltot;
  }
#pragma unroll
  for (int r = 0; r < 4; ++r)
    o[((size_t)(s0 + 4 * g + r) * NH + h) * HD + wid * 16 + l15] = outv[r];
}

// ---------------------------------------------------------------------------
// RMS-norm + sigmoid gate (vectorized x4); emits bf16.
// ---------------------------------------------------------------------------
__global__ __launch_bounds__(256) void postproc(const float* __restrict__ o,
                                                const float* __restrict__ g,
                                                const float* __restrict__ w,
                                                unsigned short* __restrict__ o2h) {
  int base = (blockIdx.x * 256 + threadIdx.x) * 4;
  int l16 = threadIdx.x & 15;  // 16 lanes per 64-elem row
  float4 val = *reinterpret_cast<const float4*>(&o[base]);
  float ss = val.x * val.x + val.y * val.y + val.z * val.z + val.w * val.w;
#pragma unroll
  for (int off = 1; off < 16; off <<= 1) ss += __shfl_xor(ss, off);
  float r = rsqrtf(ss * (1.0f / HD) + 1e-6f);
  float4 gv = *reinterpret_cast<const float4*>(&g[base]);
  float f[4] = {val.x, val.y, val.z, val.w};
  float gg[4] = {gv.x, gv.y, gv.z, gv.w};
  unsigned short u[4];
#pragma unroll
  for (int j = 0; j < 4; ++j) {
    float sig = 1.0f / (1.0f + expf(-gg[j]));
    u[j] = f2bf(f[j] * r * w[l16 * 4 + j] * sig);
  }
  *reinterpret_cast<ushort4*>(&o2h[base]) = make_ushort4(u[0], u[1], u[2], u[3]);
}

// ---------------------------------------------------------------------------
extern "C" void kernel_launch(void* const* d_in, const int* in_sizes, int n_in,
                              void* d_out, int out_size, void* d_ws, size_t ws_size,
                              hipStream_t stream) {
  const float* x   = (const float*)d_in[0];
  const float* Wq  = (const float*)d_in[1];
  const float* Wk  = (const float*)d_in[2];
  const float* Wv  = (const float*)d_in[3];
  const float* Wo  = (const float*)d_in[4];
  const float* Wg1 = (const float*)d_in[5];
  const float* Wg2 = (const float*)d_in[6];
  const float* onw = (const float*)d_in[7];
  float* out = (float*)d_out;

  const size_t BIG = (size_t)S_LEN * D_DIM;  // 4M elements
  float* q    = (float*)d_ws;
  float* k    = q + BIG;
  float* v    = k + BIG;
  float* o    = v + BIG;
  float* gbuf = o + BIG;
  float* kg   = gbuf + BIG;                    // NCH*NH*HD
  int* amask  = (int*)(kg + NCH * NH * HD);    // NH*S
  float2* rtab = (float2*)(amask + NH * S_LEN);  // S*32 float2
  unsigned short* xh  = (unsigned short*)(rtab + S_LEN * 32);
  unsigned short* xl  = xh + BIG;
  unsigned short* whq = xl + BIG;
  unsigned short* wlq = whq + BIG;
  unsigned short* whk = wlq + BIG;
  unsigned short* wlk = whk + BIG;
  unsigned short* whv = wlk + BIG;
  unsigned short* whg = whv + BIG;
  unsigned short* who = whg + BIG;
  unsigned short* khf = who + BIG;
  unsigned short* vhf = khf + BIG;
  unsigned short* o2h = vhf + BIG;

  // RoPE cos/sin table
  rope_tab_k<<<(S_LEN * 32 + 255) / 256, 256, 0, stream>>>(rtab);
  // Split x into hi/lo bf16
  repack_x_hl<<<(int)(BIG / 4 / 256), 256, 0, stream>>>(x, xh, xl);
  // Fused weight repacks: Wq(lo), Wk(lo), Wv, Wo
  {
    RT4 rt;
    rt.W[0] = Wq; rt.hiT[0] = whq; rt.loT[0] = wlq; rt.has_lo[0] = 1;
    rt.W[1] = Wk; rt.hiT[1] = whk; rt.loT[1] = wlk; rt.has_lo[1] = 1;
    rt.W[2] = Wv; rt.hiT[2] = whv; rt.loT[2] = whv; rt.has_lo[2] = 0;
    rt.W[3] = Wo; rt.hiT[3] = who; rt.loT[3] = who; rt.has_lo[3] = 0;
    repack_T4<<<dim3(32, 32, 4), 256, 0, stream>>>(rt);
  }
  // W' = Wg1 @ Wg2 -> whg (bf16 transposed, direct)
  sgemm_f32T<<<dim3(16, 16), 256, 0, stream>>>(Wg1, Wg2, whg, D_DIM, D_DIM, HD);

  // Fused Q(3) K(3) V(1) G(1) projections + RoPE epilogue on Q,K
  {
    QKVG gg;
    gg.xh = xh; gg.xl = xl;
    gg.wh[0] = whq; gg.wh[1] = whk; gg.wh[2] = whv; gg.wh[3] = whg;
    gg.wl[0] = wlq; gg.wl[1] = wlk; gg.wl[2] = nullptr; gg.wl[3] = nullptr;
    gg.C[0] = q; gg.C[1] = k; gg.C[2] = v; gg.C[3] = gbuf;
    gg.np[0] = 3; gg.np[1] = 3; gg.np[2] = 1; gg.np[3] = 1;
    gg.rtab = rtab;
    gemm_qkvg<<<1024, 256, 0, stream>>>(gg);
  }

  // Chunk means + gating (fp32)
  chunk_mean<<<(NCH * NH * HD + 255) / 256, 256, 0, stream>>>(k, kg);
  gate_topk<<<dim3(S_LEN / 4, NH), 256, 0, stream>>>(q, kg, amask);
  // Fragment-major K/V repack (fused)
  repack_kvf<<<dim3(S_LEN / 64, NH), 256, 0, stream>>>(k, v, khf, vhf);
  // Attention (overwrites o)
  attn_mfma<<<(S_LEN / 16) * NH, 256, 0, stream>>>(q, khf, vhf, amask, o);
  // RMS-norm + sigmoid gate -> bf16
  postproc<<<(int)(BIG / 4 / 256), 256, 0, stream>>>(o, gbuf, onw, o2h);
  // out = o2 @ Wo
  {
    G3 g3{{o2h, o2h, o2h}, {who, who, who}, 1};
    gemm_bt<<<(S_LEN / 64) * (D_DIM / 128), 256, 0, stream>>>(g3, out, S_LEN, D_DIM, D_DIM);
  }
}